// Round 1
// baseline (586.361 us; speedup 1.0000x reference)
//
#include <hip/hip_runtime.h>

#define NN 50000
#define HID 64
#define NE 800000
#define NP 100000
#define BN_EPS 1e-5f

static inline size_t alignup(size_t x) { return (x + 255) & ~(size_t)255; }

__global__ __launch_bounds__(256) void k_init_deg(int* deg) {
    int i = blockIdx.x * blockDim.x + threadIdx.x;
    if (i < NN) deg[i] = 1;   // self-loop
}

__global__ __launch_bounds__(256) void k_count_deg(const int* col, int* deg) {
    int e = blockIdx.x * blockDim.x + threadIdx.x;
    if (e < NE) atomicAdd(&deg[col[e]], 1);
}

__global__ __launch_bounds__(256) void k_dis(const int* deg, float* dis) {
    int i = blockIdx.x * blockDim.x + threadIdx.x;
    if (i < NN) dis[i] = rsqrtf((float)deg[i]);
}

// x = concat(id_emb, n2v) @ proj_w + proj_b   (K=128, 4 nodes/block)
__global__ __launch_bounds__(256) void k_proj(const float* __restrict__ id_emb,
                                              const float* __restrict__ n2v,
                                              const float* __restrict__ W,
                                              const float* __restrict__ b,
                                              float* __restrict__ x) {
    __shared__ float Wl[128 * 64];
    __shared__ float rowbuf[4][128];
    int tid = threadIdx.x;
    for (int i = tid; i < 128 * 64; i += 256) Wl[i] = W[i];
    int node0 = blockIdx.x * 4;
    for (int i = tid; i < 4 * 128; i += 256) {
        int ln = i >> 7, k = i & 127;
        int n = node0 + ln;
        rowbuf[ln][k] = (k < 64) ? id_emb[n * 64 + k] : n2v[n * 64 + (k - 64)];
    }
    __syncthreads();
    int ln = tid >> 6, f = tid & 63;
    float acc = b[f];
#pragma unroll
    for (int k = 0; k < 128; ++k)
        acc += rowbuf[ln][k] * Wl[k * 64 + f];
    x[(node0 + ln) * 64 + f] = acc;
}

// h = x @ W   (K=64, 4 nodes/block)
__global__ __launch_bounds__(256) void k_gemm64(const float* __restrict__ x,
                                                const float* __restrict__ W,
                                                float* __restrict__ h) {
    __shared__ float Wl[64 * 64];
    __shared__ float rowbuf[4][64];
    int tid = threadIdx.x;
    for (int i = tid; i < 64 * 64; i += 256) Wl[i] = W[i];
    int node0 = blockIdx.x * 4;
    for (int i = tid; i < 4 * 64; i += 256) rowbuf[i >> 6][i & 63] = x[node0 * 64 + i];
    __syncthreads();
    int ln = tid >> 6, f = tid & 63;
    float acc = 0.f;
#pragma unroll
    for (int k = 0; k < 64; ++k)
        acc += rowbuf[ln][k] * Wl[k * 64 + f];
    h[(node0 + ln) * 64 + f] = acc;
}

// agg init with self-loop term: agg[i][f] = h[i][f] / deg[i]
__global__ __launch_bounds__(256) void k_selfloop(const float* __restrict__ h,
                                                  const float* __restrict__ dis,
                                                  float* __restrict__ agg) {
    int i = blockIdx.x * blockDim.x + threadIdx.x;
    if (i < NN * HID) {
        float d = dis[i >> 6];
        agg[i] = h[i] * d * d;
    }
}

// edge scatter: agg[dst] += dis[src]*dis[dst] * h[src]   (one wave per edge)
__global__ __launch_bounds__(256) void k_scatter(const int* __restrict__ row,
                                                 const int* __restrict__ col,
                                                 const float* __restrict__ dis,
                                                 const float* __restrict__ h,
                                                 float* __restrict__ agg) {
    int gw = (blockIdx.x * blockDim.x + threadIdx.x) >> 6;
    int f = threadIdx.x & 63;
    int nw = (gridDim.x * blockDim.x) >> 6;
    for (int e = gw; e < NE; e += nw) {
        int s = row[e], d = col[e];
        float w = dis[s] * dis[d];
        atomicAdd(&agg[d * 64 + f], w * h[s * 64 + f]);
    }
}

__global__ void k_zero_sums(float* sums) {
    int i = threadIdx.x;
    if (i < 128) sums[i] = 0.f;
}

// per-column sum & sumsq partials -> atomics into sums[0:64]=sum, sums[64:128]=sumsq
__global__ __launch_bounds__(256) void k_bnstats(const float* __restrict__ agg,
                                                 float* __restrict__ sums) {
    __shared__ float ls[2][4][64];
    int tid = threadIdx.x;
    int f = tid & 63, rg = tid >> 6;
    float s = 0.f, s2 = 0.f;
    int rows_per_block = (NN + gridDim.x - 1) / gridDim.x;
    int r0 = blockIdx.x * rows_per_block;
    int r1 = r0 + rows_per_block;
    if (r1 > NN) r1 = NN;
    for (int r = r0 + rg; r < r1; r += 4) {
        float v = agg[r * 64 + f];
        s += v;
        s2 += v * v;
    }
    ls[0][rg][f] = s;
    ls[1][rg][f] = s2;
    __syncthreads();
    if (tid < 64) {
        float a = ls[0][0][tid] + ls[0][1][tid] + ls[0][2][tid] + ls[0][3][tid];
        atomicAdd(&sums[tid], a);
    } else if (tid < 128) {
        int q = tid - 64;
        float a = ls[1][0][q] + ls[1][1][q] + ls[1][2][q] + ls[1][3][q];
        atomicAdd(&sums[64 + q], a);
    }
}

// x += relu((agg - mu) * rstd * gamma + beta)
__global__ __launch_bounds__(256) void k_bnupdate(const float* __restrict__ agg,
                                                  const float* __restrict__ sums,
                                                  const float* __restrict__ gamma,
                                                  const float* __restrict__ beta,
                                                  float* __restrict__ x) {
    int i = blockIdx.x * blockDim.x + threadIdx.x;
    if (i >= NN * HID) return;
    int f = i & 63;
    const float invn = 1.0f / (float)NN;
    float mu = sums[f] * invn;
    float var = sums[64 + f] * invn - mu * mu;
    float rstd = rsqrtf(var + BN_EPS);
    float xn = (agg[i] - mu) * rstd * gamma[f] + beta[f];
    x[i] += fmaxf(xn, 0.f);
}

// out[p] = dot(z[a], z[b])   (one wave per pred edge)
__global__ __launch_bounds__(256) void k_decode(const int* __restrict__ pred,
                                                const float* __restrict__ z,
                                                float* __restrict__ out) {
    int gw = (blockIdx.x * blockDim.x + threadIdx.x) >> 6;
    int f = threadIdx.x & 63;
    int nw = (gridDim.x * blockDim.x) >> 6;
    for (int p = gw; p < NP; p += nw) {
        int a = pred[2 * p], b = pred[2 * p + 1];
        float v = z[a * 64 + f] * z[b * 64 + f];
        for (int off = 32; off; off >>= 1) v += __shfl_xor(v, off);
        if (f == 0) out[p] = v;
    }
}

extern "C" void kernel_launch(void* const* d_in, const int* in_sizes, int n_in,
                              void* d_out, int out_size, void* d_ws, size_t ws_size,
                              hipStream_t stream) {
    const int* edge_index = (const int*)d_in[0];   // [2][NE]
    const int* pred       = (const int*)d_in[1];   // [NP][2]
    const float* id_emb   = (const float*)d_in[2];
    const float* n2v      = (const float*)d_in[3];
    const float* proj_w   = (const float*)d_in[4];
    const float* proj_b   = (const float*)d_in[5];
    const float* conv_w   = (const float*)d_in[6]; // [2][64][64]
    // d_in[7] conv_b: cancels exactly inside BatchNorm -> skipped
    const float* gamma    = (const float*)d_in[8];
    const float* beta     = (const float*)d_in[9];
    float* out = (float*)d_out;

    char* ws = (char*)d_ws;
    size_t off = 0;
    float* dis = (float*)(ws + off); off += alignup(NN * 4);
    int* deg   = (int*)(ws + off);   off += alignup(NN * 4);
    float* x   = (float*)(ws + off); off += alignup((size_t)NN * 64 * 4);
    float* h   = (float*)(ws + off); off += alignup((size_t)NN * 64 * 4);
    float* agg = (float*)(ws + off); off += alignup((size_t)NN * 64 * 4);
    float* sums = (float*)(ws + off);

    const int* row = edge_index;
    const int* col = edge_index + NE;

    k_init_deg<<<(NN + 255) / 256, 256, 0, stream>>>(deg);
    k_count_deg<<<(NE + 255) / 256, 256, 0, stream>>>(col, deg);
    k_dis<<<(NN + 255) / 256, 256, 0, stream>>>(deg, dis);

    k_proj<<<NN / 4, 256, 0, stream>>>(id_emb, n2v, proj_w, proj_b, x);

    for (int l = 0; l < 2; ++l) {
        k_gemm64<<<NN / 4, 256, 0, stream>>>(x, conv_w + l * 64 * 64, h);
        k_selfloop<<<(NN * HID + 255) / 256, 256, 0, stream>>>(h, dis, agg);
        k_scatter<<<2048, 256, 0, stream>>>(row, col, dis, h, agg);
        k_zero_sums<<<1, 128, 0, stream>>>(sums);
        k_bnstats<<<256, 256, 0, stream>>>(agg, sums);
        k_bnupdate<<<(NN * HID + 255) / 256, 256, 0, stream>>>(agg, sums, gamma + l * 64, beta + l * 64, x);
    }

    k_decode<<<1024, 256, 0, stream>>>(pred, x, out);
}

// Round 2
// 387.761 us; speedup vs baseline: 1.5122x; 1.5122x over previous
//
#include <hip/hip_runtime.h>

#define NN 50000
#define HID 64
#define NE 800000
#define NP 100000
#define BN_EPS 1e-5f
#define NB1 196   // ceil(NN/256) blocks for scan

static inline size_t alignup(size_t x) { return (x + 255) & ~(size_t)255; }

// ---------- degree / normalization ----------

__global__ __launch_bounds__(256) void k_count(const int* __restrict__ col, int* __restrict__ cnt) {
    int e = blockIdx.x * blockDim.x + threadIdx.x;
    if (e < NE) atomicAdd(&cnt[col[e]], 1);
}

__global__ __launch_bounds__(256) void k_dis(const int* __restrict__ cnt, float* __restrict__ dis) {
    int i = blockIdx.x * blockDim.x + threadIdx.x;
    if (i < NN) dis[i] = rsqrtf((float)(cnt[i] + 1));   // +1 self-loop
}

// ---------- exclusive scan of cnt -> offs (3 phases) ----------

__global__ __launch_bounds__(256) void k_scan1(const int* __restrict__ cnt,
                                               int* __restrict__ offs, int* __restrict__ bsum) {
    __shared__ int s[256];
    int t = threadIdx.x;
    int i = blockIdx.x * 256 + t;
    int v = (i < NN) ? cnt[i] : 0;
    s[t] = v;
    __syncthreads();
    for (int off = 1; off < 256; off <<= 1) {
        int add = (t >= off) ? s[t - off] : 0;
        __syncthreads();
        s[t] += add;
        __syncthreads();
    }
    if (i < NN) offs[i] = s[t] - v;   // exclusive within block
    if (t == 255) bsum[blockIdx.x] = s[255];
}

__global__ __launch_bounds__(256) void k_scan2(int* __restrict__ bsum, int* __restrict__ boff) {
    __shared__ int s[256];
    int t = threadIdx.x;
    int v = (t < NB1) ? bsum[t] : 0;
    s[t] = v;
    __syncthreads();
    for (int off = 1; off < 256; off <<= 1) {
        int add = (t >= off) ? s[t - off] : 0;
        __syncthreads();
        s[t] += add;
        __syncthreads();
    }
    if (t < NB1) boff[t] = s[t] - v;   // exclusive block offsets
}

__global__ __launch_bounds__(256) void k_scan3(int* __restrict__ offs, const int* __restrict__ boff,
                                               int* __restrict__ cursor) {
    int i = blockIdx.x * blockDim.x + threadIdx.x;
    if (i < NN) {
        int o = offs[i] + boff[i >> 8];
        offs[i] = o;
        cursor[i] = o;
    }
    if (i == 0) offs[NN] = NE;
}

// ---------- CSR fill: csr_src[pos] = src, csr_w[pos] = dis[src]*dis[dst] ----------

__global__ __launch_bounds__(256) void k_fill(const int* __restrict__ row, const int* __restrict__ col,
                                              const float* __restrict__ dis,
                                              int* __restrict__ cursor,
                                              int* __restrict__ csr_src, float* __restrict__ csr_w) {
    int e = blockIdx.x * blockDim.x + threadIdx.x;
    if (e >= NE) return;
    int s = row[e], d = col[e];
    int pos = atomicAdd(&cursor[d], 1);
    csr_src[pos] = s;
    csr_w[pos] = dis[s] * dis[d];
}

// ---------- input projection: x = concat(id,n2v) @ W + b ----------

__global__ __launch_bounds__(256) void k_proj(const float* __restrict__ id_emb,
                                              const float* __restrict__ n2v,
                                              const float* __restrict__ W,
                                              const float* __restrict__ b,
                                              float* __restrict__ x) {
    __shared__ float Wl[128 * 64];
    __shared__ float rowbuf[4][128];
    int tid = threadIdx.x;
    for (int i = tid; i < 128 * 64; i += 256) Wl[i] = W[i];
    int node0 = blockIdx.x * 4;
    for (int i = tid; i < 4 * 128; i += 256) {
        int ln = i >> 7, k = i & 127;
        int n = node0 + ln;
        rowbuf[ln][k] = (k < 64) ? id_emb[n * 64 + k] : n2v[n * 64 + (k - 64)];
    }
    __syncthreads();
    int ln = tid >> 6, f = tid & 63;
    float acc = b[f];
#pragma unroll
    for (int k = 0; k < 128; ++k)
        acc += rowbuf[ln][k] * Wl[k * 64 + f];
    x[(node0 + ln) * 64 + f] = acc;
}

// ---------- h = x @ W ----------

__global__ __launch_bounds__(256) void k_gemm64(const float* __restrict__ x,
                                                const float* __restrict__ W,
                                                float* __restrict__ h) {
    __shared__ float Wl[64 * 64];
    __shared__ float rowbuf[4][64];
    int tid = threadIdx.x;
    for (int i = tid; i < 64 * 64; i += 256) Wl[i] = W[i];
    int node0 = blockIdx.x * 4;
    for (int i = tid; i < 4 * 64; i += 256) rowbuf[i >> 6][i & 63] = x[node0 * 64 + i];
    __syncthreads();
    int ln = tid >> 6, f = tid & 63;
    float acc = 0.f;
#pragma unroll
    for (int k = 0; k < 64; ++k)
        acc += rowbuf[ln][k] * Wl[k * 64 + f];
    h[(node0 + ln) * 64 + f] = acc;
}

// ---------- CSR gather: agg[i] = h[i]/deg[i] + sum_j w_j * h[src_j]  (one wave/node) ----------

__global__ __launch_bounds__(256) void k_gather(const int* __restrict__ offs,
                                                const int* __restrict__ csr_src,
                                                const float* __restrict__ csr_w,
                                                const float* __restrict__ dis,
                                                const float* __restrict__ h,
                                                float* __restrict__ agg) {
    int w = (blockIdx.x * blockDim.x + threadIdx.x) >> 6;
    int f = threadIdx.x & 63;
    if (w >= NN) return;
    float di = dis[w];
    float acc = di * di * h[w * 64 + f];     // self-loop term (norm = 1/deg)
    int j = offs[w], j1 = offs[w + 1];
    for (; j + 1 < j1; j += 2) {
        int s0 = csr_src[j], s1 = csr_src[j + 1];
        float w0 = csr_w[j], w1 = csr_w[j + 1];
        acc += w0 * h[s0 * 64 + f];
        acc += w1 * h[s1 * 64 + f];
    }
    if (j < j1) acc += csr_w[j] * h[csr_src[j] * 64 + f];
    agg[w * 64 + f] = acc;
}

// ---------- BatchNorm ----------

__global__ void k_zero_sums(float* sums) {
    int i = threadIdx.x;
    if (i < 128) sums[i] = 0.f;
}

__global__ __launch_bounds__(256) void k_bnstats(const float* __restrict__ agg,
                                                 float* __restrict__ sums) {
    __shared__ float ls[2][4][64];
    int tid = threadIdx.x;
    int f = tid & 63, rg = tid >> 6;
    float s = 0.f, s2 = 0.f;
    int rows_per_block = (NN + gridDim.x - 1) / gridDim.x;
    int r0 = blockIdx.x * rows_per_block;
    int r1 = r0 + rows_per_block;
    if (r1 > NN) r1 = NN;
    for (int r = r0 + rg; r < r1; r += 4) {
        float v = agg[r * 64 + f];
        s += v;
        s2 += v * v;
    }
    ls[0][rg][f] = s;
    ls[1][rg][f] = s2;
    __syncthreads();
    if (tid < 64) {
        float a = ls[0][0][tid] + ls[0][1][tid] + ls[0][2][tid] + ls[0][3][tid];
        atomicAdd(&sums[tid], a);
    } else if (tid < 128) {
        int q = tid - 64;
        float a = ls[1][0][q] + ls[1][1][q] + ls[1][2][q] + ls[1][3][q];
        atomicAdd(&sums[64 + q], a);
    }
}

__global__ __launch_bounds__(256) void k_bnupdate(const float* __restrict__ agg,
                                                  const float* __restrict__ sums,
                                                  const float* __restrict__ gamma,
                                                  const float* __restrict__ beta,
                                                  float* __restrict__ x) {
    int i = blockIdx.x * blockDim.x + threadIdx.x;
    if (i >= NN * HID) return;
    int f = i & 63;
    const float invn = 1.0f / (float)NN;
    float mu = sums[f] * invn;
    float var = sums[64 + f] * invn - mu * mu;
    float rstd = rsqrtf(var + BN_EPS);
    float xn = (agg[i] - mu) * rstd * gamma[f] + beta[f];
    x[i] += fmaxf(xn, 0.f);
}

// ---------- decoder ----------

__global__ __launch_bounds__(256) void k_decode(const int* __restrict__ pred,
                                                const float* __restrict__ z,
                                                float* __restrict__ out) {
    int gw = (blockIdx.x * blockDim.x + threadIdx.x) >> 6;
    int f = threadIdx.x & 63;
    int nw = (gridDim.x * blockDim.x) >> 6;
    for (int p = gw; p < NP; p += nw) {
        int a = pred[2 * p], b = pred[2 * p + 1];
        float v = z[a * 64 + f] * z[b * 64 + f];
        for (int off = 32; off; off >>= 1) v += __shfl_xor(v, off);
        if (f == 0) out[p] = v;
    }
}

extern "C" void kernel_launch(void* const* d_in, const int* in_sizes, int n_in,
                              void* d_out, int out_size, void* d_ws, size_t ws_size,
                              hipStream_t stream) {
    const int* edge_index = (const int*)d_in[0];   // [2][NE]
    const int* pred       = (const int*)d_in[1];   // [NP][2]
    const float* id_emb   = (const float*)d_in[2];
    const float* n2v      = (const float*)d_in[3];
    const float* proj_w   = (const float*)d_in[4];
    const float* proj_b   = (const float*)d_in[5];
    const float* conv_w   = (const float*)d_in[6]; // [2][64][64]
    // d_in[7] conv_b cancels inside BatchNorm -> skipped
    const float* gamma    = (const float*)d_in[8];
    const float* beta     = (const float*)d_in[9];
    float* out = (float*)d_out;

    char* ws = (char*)d_ws;
    size_t off = 0;
    float* dis   = (float*)(ws + off); off += alignup(NN * 4);
    int* cnt     = (int*)(ws + off);   off += alignup(NN * 4);
    int* offs    = (int*)(ws + off);   off += alignup((NN + 1) * 4);
    int* cursor  = (int*)(ws + off);   off += alignup(NN * 4);
    int* bsum    = (int*)(ws + off);   off += alignup(NB1 * 4);
    int* boff    = (int*)(ws + off);   off += alignup(NB1 * 4);
    int* csr_src = (int*)(ws + off);   off += alignup((size_t)NE * 4);
    float* csr_w = (float*)(ws + off); off += alignup((size_t)NE * 4);
    float* x     = (float*)(ws + off); off += alignup((size_t)NN * 64 * 4);
    float* h     = (float*)(ws + off); off += alignup((size_t)NN * 64 * 4);
    float* agg   = (float*)(ws + off); off += alignup((size_t)NN * 64 * 4);
    float* sums  = (float*)(ws + off);

    const int* row = edge_index;
    const int* col = edge_index + NE;

    // CSR build (once, reused for both layers)
    hipMemsetAsync(cnt, 0, NN * 4, stream);
    k_count<<<(NE + 255) / 256, 256, 0, stream>>>(col, cnt);
    k_dis<<<(NN + 255) / 256, 256, 0, stream>>>(cnt, dis);
    k_scan1<<<NB1, 256, 0, stream>>>(cnt, offs, bsum);
    k_scan2<<<1, 256, 0, stream>>>(bsum, boff);
    k_scan3<<<NB1, 256, 0, stream>>>(offs, boff, cursor);
    k_fill<<<(NE + 255) / 256, 256, 0, stream>>>(row, col, dis, cursor, csr_src, csr_w);

    k_proj<<<NN / 4, 256, 0, stream>>>(id_emb, n2v, proj_w, proj_b, x);

    for (int l = 0; l < 2; ++l) {
        k_gemm64<<<NN / 4, 256, 0, stream>>>(x, conv_w + l * 64 * 64, h);
        k_gather<<<(NN * 64 + 255) / 256, 256, 0, stream>>>(offs, csr_src, csr_w, dis, h, agg);
        k_zero_sums<<<1, 128, 0, stream>>>(sums);
        k_bnstats<<<256, 256, 0, stream>>>(agg, sums);
        k_bnupdate<<<(NN * HID + 255) / 256, 256, 0, stream>>>(agg, sums, gamma + l * 64, beta + l * 64, x);
    }

    k_decode<<<1024, 256, 0, stream>>>(pred, x, out);
}

// Round 3
// 299.708 us; speedup vs baseline: 1.9564x; 1.2938x over previous
//
#include <hip/hip_runtime.h>

#define NN 50000
#define HID 64
#define NE 800000
#define NP 100000
#define BN_EPS 1e-5f
#define NB1 196   // ceil(NN/256) blocks for scan

static inline size_t alignup(size_t x) { return (x + 255) & ~(size_t)255; }

// ---------- degree / normalization ----------

__global__ __launch_bounds__(256) void k_count(const int* __restrict__ col, int* __restrict__ cnt) {
    int e = blockIdx.x * blockDim.x + threadIdx.x;
    if (e < NE) atomicAdd(&cnt[col[e]], 1);
}

__global__ __launch_bounds__(256) void k_dis(const int* __restrict__ cnt, float* __restrict__ dis,
                                             float* __restrict__ sums) {
    int i = blockIdx.x * blockDim.x + threadIdx.x;
    if (i < NN) dis[i] = rsqrtf((float)(cnt[i] + 1));   // +1 self-loop
    if (i < 256) sums[i] = 0.f;                          // zero BN accumulators (2 layers x 128)
}

// ---------- exclusive scan of cnt -> offs (3 phases) ----------

__global__ __launch_bounds__(256) void k_scan1(const int* __restrict__ cnt,
                                               int* __restrict__ offs, int* __restrict__ bsum) {
    __shared__ int s[256];
    int t = threadIdx.x;
    int i = blockIdx.x * 256 + t;
    int v = (i < NN) ? cnt[i] : 0;
    s[t] = v;
    __syncthreads();
    for (int off = 1; off < 256; off <<= 1) {
        int add = (t >= off) ? s[t - off] : 0;
        __syncthreads();
        s[t] += add;
        __syncthreads();
    }
    if (i < NN) offs[i] = s[t] - v;
    if (t == 255) bsum[blockIdx.x] = s[255];
}

__global__ __launch_bounds__(256) void k_scan2(int* __restrict__ bsum, int* __restrict__ boff) {
    __shared__ int s[256];
    int t = threadIdx.x;
    int v = (t < NB1) ? bsum[t] : 0;
    s[t] = v;
    __syncthreads();
    for (int off = 1; off < 256; off <<= 1) {
        int add = (t >= off) ? s[t - off] : 0;
        __syncthreads();
        s[t] += add;
        __syncthreads();
    }
    if (t < NB1) boff[t] = s[t] - v;
}

__global__ __launch_bounds__(256) void k_scan3(int* __restrict__ offs, const int* __restrict__ boff,
                                               int* __restrict__ cursor) {
    int i = blockIdx.x * blockDim.x + threadIdx.x;
    if (i < NN) {
        int o = offs[i] + boff[i >> 8];
        offs[i] = o;
        cursor[i] = o;
    }
    if (i == 0) offs[NN] = NE;
}

// ---------- CSR fill ----------

__global__ __launch_bounds__(256) void k_fill(const int* __restrict__ row, const int* __restrict__ col,
                                              const float* __restrict__ dis,
                                              int* __restrict__ cursor,
                                              int* __restrict__ csr_src, float* __restrict__ csr_w) {
    int e = blockIdx.x * blockDim.x + threadIdx.x;
    if (e >= NE) return;
    int s = row[e], d = col[e];
    int pos = atomicAdd(&cursor[d], 1);
    csr_src[pos] = s;
    csr_w[pos] = dis[s] * dis[d];
}

// ---------- input projection (grid-stride, W resident) ----------

__global__ __launch_bounds__(256) void k_proj(const float* __restrict__ id_emb,
                                              const float* __restrict__ n2v,
                                              const float* __restrict__ W,
                                              const float* __restrict__ b,
                                              float* __restrict__ x) {
    __shared__ float Wl[128 * 64];
    __shared__ float rowbuf[4][128];
    int tid = threadIdx.x;
    for (int i = tid; i < 128 * 64; i += 256) Wl[i] = W[i];
    int ln = tid >> 6, f = tid & 63;
    float bf = b[f];
    for (int g = blockIdx.x; g < NN / 4; g += gridDim.x) {
        __syncthreads();   // also covers initial Wl load
        int node0 = g * 4;
        for (int i = tid; i < 512; i += 256) {
            int l2 = i >> 7, k = i & 127;
            int n = node0 + l2;
            rowbuf[l2][k] = (k < 64) ? id_emb[n * 64 + k] : n2v[n * 64 + (k - 64)];
        }
        __syncthreads();
        float acc = bf;
#pragma unroll
        for (int k = 0; k < 128; ++k)
            acc += rowbuf[ln][k] * Wl[k * 64 + f];
        x[(node0 + ln) * 64 + f] = acc;
    }
}

// ---------- CSR gather on x: t[i] = x[i]/deg[i] + sum_j w_j x[src_j]  (4 nodes/wave, float4) ----------

__global__ __launch_bounds__(256) void k_gather(const int* __restrict__ offs,
                                                const int* __restrict__ csr_src,
                                                const float* __restrict__ csr_w,
                                                const float* __restrict__ dis,
                                                const float* __restrict__ x,
                                                float* __restrict__ t) {
    int gw = (blockIdx.x * blockDim.x + threadIdx.x) >> 6;
    int lane = threadIdx.x & 63;
    int sub = lane >> 4, q = lane & 15;
    int w = gw * 4 + sub;
    if (w >= NN) return;
    const float4* x4 = (const float4*)x;
    float di = dis[w];
    float dd = di * di;
    float4 v = x4[w * 16 + q];
    float4 acc = make_float4(dd * v.x, dd * v.y, dd * v.z, dd * v.w);
    int j = offs[w], j1 = offs[w + 1];
    for (; j + 1 < j1; j += 2) {
        int s0 = csr_src[j], s1 = csr_src[j + 1];
        float w0 = csr_w[j], w1 = csr_w[j + 1];
        float4 a = x4[s0 * 16 + q];
        float4 c = x4[s1 * 16 + q];
        acc.x += w0 * a.x + w1 * c.x;
        acc.y += w0 * a.y + w1 * c.y;
        acc.z += w0 * a.z + w1 * c.z;
        acc.w += w0 * a.w + w1 * c.w;
    }
    if (j < j1) {
        int s0 = csr_src[j];
        float w0 = csr_w[j];
        float4 a = x4[s0 * 16 + q];
        acc.x += w0 * a.x; acc.y += w0 * a.y; acc.z += w0 * a.z; acc.w += w0 * a.w;
    }
    ((float4*)t)[w * 16 + q] = acc;
}

// ---------- agg = t @ W with fused BN column stats (grid-stride, W resident) ----------

__global__ __launch_bounds__(256) void k_gemm_stats(const float* __restrict__ t,
                                                    const float* __restrict__ W,
                                                    float* __restrict__ agg,
                                                    float* __restrict__ sums) {
    __shared__ float Wl[64 * 64];
    __shared__ float rowbuf[4][64];
    __shared__ float ls[2][4][64];
    int tid = threadIdx.x;
    for (int i = tid; i < 64 * 64; i += 256) Wl[i] = W[i];
    int ln = tid >> 6, f = tid & 63;
    float s = 0.f, s2 = 0.f;
    for (int g = blockIdx.x; g < NN / 4; g += gridDim.x) {
        __syncthreads();   // also covers initial Wl load
        rowbuf[ln][f] = t[g * 256 + tid];
        __syncthreads();
        float acc = 0.f;
#pragma unroll
        for (int k = 0; k < 64; ++k)
            acc += rowbuf[ln][k] * Wl[k * 64 + f];
        agg[g * 256 + tid] = acc;
        s += acc;
        s2 += acc * acc;
    }
    ls[0][ln][f] = s;
    ls[1][ln][f] = s2;
    __syncthreads();
    if (tid < 64) {
        atomicAdd(&sums[tid], ls[0][0][tid] + ls[0][1][tid] + ls[0][2][tid] + ls[0][3][tid]);
    } else if (tid < 128) {
        int q = tid - 64;
        atomicAdd(&sums[64 + q], ls[1][0][q] + ls[1][1][q] + ls[1][2][q] + ls[1][3][q]);
    }
}

// ---------- x += relu(BN(agg)) ----------

__global__ __launch_bounds__(256) void k_bnupdate(const float* __restrict__ agg,
                                                  const float* __restrict__ sums,
                                                  const float* __restrict__ gamma,
                                                  const float* __restrict__ beta,
                                                  float* __restrict__ x) {
    int i = blockIdx.x * blockDim.x + threadIdx.x;
    if (i >= NN * HID) return;
    int f = i & 63;
    const float invn = 1.0f / (float)NN;
    float mu = sums[f] * invn;
    float var = sums[64 + f] * invn - mu * mu;
    float rstd = rsqrtf(var + BN_EPS);
    float xn = (agg[i] - mu) * rstd * gamma[f] + beta[f];
    x[i] += fmaxf(xn, 0.f);
}

// ---------- decoder (4 edges/wave, float4) ----------

__global__ __launch_bounds__(256) void k_decode(const int* __restrict__ pred,
                                                const float* __restrict__ z,
                                                float* __restrict__ out) {
    int gw = (blockIdx.x * blockDim.x + threadIdx.x) >> 6;
    int lane = threadIdx.x & 63;
    int sub = lane >> 4, q = lane & 15;
    int p = gw * 4 + sub;
    if (p >= NP) return;
    const float4* z4 = (const float4*)z;
    int a = pred[2 * p], b = pred[2 * p + 1];
    float4 va = z4[a * 16 + q];
    float4 vb = z4[b * 16 + q];
    float v = va.x * vb.x + va.y * vb.y + va.z * vb.z + va.w * vb.w;
    v += __shfl_xor(v, 1);
    v += __shfl_xor(v, 2);
    v += __shfl_xor(v, 4);
    v += __shfl_xor(v, 8);
    if (q == 0) out[p] = v;
}

extern "C" void kernel_launch(void* const* d_in, const int* in_sizes, int n_in,
                              void* d_out, int out_size, void* d_ws, size_t ws_size,
                              hipStream_t stream) {
    const int* edge_index = (const int*)d_in[0];   // [2][NE]
    const int* pred       = (const int*)d_in[1];   // [NP][2]
    const float* id_emb   = (const float*)d_in[2];
    const float* n2v      = (const float*)d_in[3];
    const float* proj_w   = (const float*)d_in[4];
    const float* proj_b   = (const float*)d_in[5];
    const float* conv_w   = (const float*)d_in[6]; // [2][64][64]
    // d_in[7] conv_b cancels inside BatchNorm -> skipped
    const float* gamma    = (const float*)d_in[8];
    const float* beta     = (const float*)d_in[9];
    float* out = (float*)d_out;

    char* ws = (char*)d_ws;
    size_t off = 0;
    float* dis   = (float*)(ws + off); off += alignup(NN * 4);
    int* cnt     = (int*)(ws + off);   off += alignup(NN * 4);
    int* offs    = (int*)(ws + off);   off += alignup((NN + 1) * 4);
    int* cursor  = (int*)(ws + off);   off += alignup(NN * 4);
    int* bsum    = (int*)(ws + off);   off += alignup(NB1 * 4);
    int* boff    = (int*)(ws + off);   off += alignup(NB1 * 4);
    int* csr_src = (int*)(ws + off);   off += alignup((size_t)NE * 4);
    float* csr_w = (float*)(ws + off); off += alignup((size_t)NE * 4);
    float* x     = (float*)(ws + off); off += alignup((size_t)NN * 64 * 4);
    float* t     = (float*)(ws + off); off += alignup((size_t)NN * 64 * 4);
    float* agg   = (float*)(ws + off); off += alignup((size_t)NN * 64 * 4);
    float* sums  = (float*)(ws + off); // 256 floats (2 layers x {sum,sumsq})

    const int* row = edge_index;
    const int* col = edge_index + NE;

    // CSR build (once, reused for both layers)
    hipMemsetAsync(cnt, 0, NN * 4, stream);
    k_count<<<(NE + 255) / 256, 256, 0, stream>>>(col, cnt);
    k_dis<<<(NN + 255) / 256, 256, 0, stream>>>(cnt, dis, sums);
    k_scan1<<<NB1, 256, 0, stream>>>(cnt, offs, bsum);
    k_scan2<<<1, 256, 0, stream>>>(bsum, boff);
    k_scan3<<<NB1, 256, 0, stream>>>(offs, boff, cursor);
    k_fill<<<(NE + 255) / 256, 256, 0, stream>>>(row, col, dis, cursor, csr_src, csr_w);

    k_proj<<<1024, 256, 0, stream>>>(id_emb, n2v, proj_w, proj_b, x);

    for (int l = 0; l < 2; ++l) {
        k_gather<<<(NN / 4 * 64 + 255) / 256, 256, 0, stream>>>(offs, csr_src, csr_w, dis, x, t);
        k_gemm_stats<<<512, 256, 0, stream>>>(t, conv_w + l * 64 * 64, agg, sums + l * 128);
        k_bnupdate<<<(NN * HID + 255) / 256, 256, 0, stream>>>(agg, sums + l * 128, gamma + l * 64, beta + l * 64, x);
    }

    k_decode<<<(NP / 4 * 64 + 255) / 256, 256, 0, stream>>>(pred, x, out);
}

// Round 4
// 299.032 us; speedup vs baseline: 1.9609x; 1.0023x over previous
//
#include <hip/hip_runtime.h>

#define NN 50000
#define HID 64
#define NE 800000
#define NP 100000
#define BN_EPS 1e-5f
#define NB1 196   // ceil(NN/256)

static inline size_t alignup(size_t x) { return (x + 255) & ~(size_t)255; }

__device__ __forceinline__ void f4fma(float a, const float4& w, float4& c) {
    c.x += a * w.x; c.y += a * w.y; c.z += a * w.z; c.w += a * w.w;
}

// ---------- degree count + per-edge rank ----------

__global__ __launch_bounds__(256) void k_count(const int* __restrict__ col,
                                               int* __restrict__ cnt, int* __restrict__ rank) {
    int e = blockIdx.x * blockDim.x + threadIdx.x;
    if (e < NE) rank[e] = atomicAdd(&cnt[col[e]], 1);
}

__global__ __launch_bounds__(256) void k_dis(const int* __restrict__ cnt, float* __restrict__ dis,
                                             float* __restrict__ sums) {
    int i = blockIdx.x * blockDim.x + threadIdx.x;
    if (i < NN) dis[i] = rsqrtf((float)(cnt[i] + 1));   // +1 self-loop
    if (i < 256) sums[i] = 0.f;                          // 2 layers x {sum,sumsq}
}

// ---------- exclusive scan of cnt -> offs ----------

__global__ __launch_bounds__(256) void k_scan1(const int* __restrict__ cnt,
                                               int* __restrict__ offs, int* __restrict__ bsum) {
    __shared__ int s[256];
    int t = threadIdx.x;
    int i = blockIdx.x * 256 + t;
    int v = (i < NN) ? cnt[i] : 0;
    s[t] = v;
    __syncthreads();
    for (int off = 1; off < 256; off <<= 1) {
        int add = (t >= off) ? s[t - off] : 0;
        __syncthreads();
        s[t] += add;
        __syncthreads();
    }
    if (i < NN) offs[i] = s[t] - v;
    if (t == 255) bsum[blockIdx.x] = s[255];
}

__global__ __launch_bounds__(256) void k_scan2(int* __restrict__ bsum, int* __restrict__ boff) {
    __shared__ int s[256];
    int t = threadIdx.x;
    int v = (t < NB1) ? bsum[t] : 0;
    s[t] = v;
    __syncthreads();
    for (int off = 1; off < 256; off <<= 1) {
        int add = (t >= off) ? s[t - off] : 0;
        __syncthreads();
        s[t] += add;
        __syncthreads();
    }
    if (t < NB1) boff[t] = s[t] - v;
}

__global__ __launch_bounds__(256) void k_scan3(int* __restrict__ offs, const int* __restrict__ boff) {
    int i = blockIdx.x * blockDim.x + threadIdx.x;
    if (i < NN) offs[i] += boff[i >> 8];
    if (i == 0) offs[NN] = NE;
}

// ---------- CSR fill: one 8B {src, w} store per edge, no atomics ----------

__global__ __launch_bounds__(256) void k_fill(const int* __restrict__ row, const int* __restrict__ col,
                                              const int* __restrict__ rank, const int* __restrict__ offs,
                                              const float* __restrict__ dis,
                                              int2* __restrict__ csr) {
    int e = blockIdx.x * blockDim.x + threadIdx.x;
    if (e >= NE) return;
    int s = row[e], d = col[e];
    int2 v;
    v.x = s;
    v.y = __float_as_int(dis[s] * dis[d]);
    csr[offs[d] + rank[e]] = v;
}

// ---------- input projection: register-tiled, 32 nodes x 64 cols per block ----------

__global__ __launch_bounds__(256) void k_proj(const float* __restrict__ id_emb,
                                              const float* __restrict__ n2v,
                                              const float* __restrict__ W,
                                              const float* __restrict__ b,
                                              float* __restrict__ x) {
    __shared__ float A[32 * 132];        // pad 132: bank-conflict-free scalar reads
    __shared__ float Wl[128 * 64];
    int tid = threadIdx.x;
    int node0 = blockIdx.x * 32;
    for (int i = tid; i < 128 * 64; i += 256) Wl[i] = W[i];
    for (int i = tid; i < 32 * 128; i += 256) {
        int ln = i >> 7, k = i & 127;
        int n = node0 + ln;
        float v = 0.f;
        if (n < NN) v = (k < 64) ? id_emb[n * 64 + k] : n2v[n * 64 + (k - 64)];
        A[ln * 132 + k] = v;
    }
    __syncthreads();
    int tr = tid >> 4, tc = tid & 15;    // thread tile: rows 2tr..2tr+1, cols 4tc..4tc+3
    const float4* W4 = (const float4*)Wl;
    float4 bb = ((const float4*)b)[tc];
    float4 c0 = bb, c1 = bb;
#pragma unroll 8
    for (int k = 0; k < 128; ++k) {
        float a0 = A[(tr * 2) * 132 + k];
        float a1 = A[(tr * 2 + 1) * 132 + k];
        float4 w = W4[k * 16 + tc];
        f4fma(a0, w, c0);
        f4fma(a1, w, c1);
    }
    int n0 = node0 + tr * 2;
    if (n0 < NN)     ((float4*)x)[n0 * 16 + tc] = c0;
    if (n0 + 1 < NN) ((float4*)x)[(n0 + 1) * 16 + tc] = c1;
}

// ---------- fused gather + GEMM + BN stats: 64 nodes per block ----------
// T[nl][:] = x[nl]/deg + sum_j w_j x[src_j]  (gathered into LDS), then agg = T @ W

__global__ __launch_bounds__(256) void k_gg(const int* __restrict__ offs,
                                            const int2* __restrict__ csr,
                                            const float* __restrict__ dis,
                                            const float* __restrict__ x,
                                            const float* __restrict__ W,
                                            float* __restrict__ agg,
                                            float* __restrict__ sums) {
    __shared__ float T[64 * 68];         // pad 68: 16B-aligned float4 rows, 2-way-free reads
    __shared__ float Wl[64 * 64];
    __shared__ float ls0[16][64];
    __shared__ float ls1[16][64];
    int tid = threadIdx.x;
    int node0 = blockIdx.x * 64;
    for (int i = tid; i < 64 * 64; i += 256) Wl[i] = W[i];
    int sub = tid >> 4, q = tid & 15;
    const float4* x4 = (const float4*)x;
    // gather phase: each 16-lane group gathers one node row (float4 per lane), 4 passes
    for (int p = 0; p < 4; ++p) {
        int nl = p * 16 + sub;
        int node = node0 + nl;
        float4 acc = make_float4(0.f, 0.f, 0.f, 0.f);
        if (node < NN) {
            float di = dis[node];
            float dd = di * di;
            float4 v = x4[node * 16 + q];
            acc = make_float4(dd * v.x, dd * v.y, dd * v.z, dd * v.w);
            int j = offs[node], j1 = offs[node + 1];
            for (; j + 1 < j1; j += 2) {
                int2 e0 = csr[j], e1 = csr[j + 1];
                float w0 = __int_as_float(e0.y), w1 = __int_as_float(e1.y);
                float4 a = x4[e0.x * 16 + q];
                float4 c = x4[e1.x * 16 + q];
                acc.x += w0 * a.x + w1 * c.x;
                acc.y += w0 * a.y + w1 * c.y;
                acc.z += w0 * a.z + w1 * c.z;
                acc.w += w0 * a.w + w1 * c.w;
            }
            if (j < j1) {
                int2 e0 = csr[j];
                float w0 = __int_as_float(e0.y);
                float4 a = x4[e0.x * 16 + q];
                acc.x += w0 * a.x; acc.y += w0 * a.y; acc.z += w0 * a.z; acc.w += w0 * a.w;
            }
        }
        ((float4*)T)[nl * 17 + q] = acc;
    }
    __syncthreads();
    // GEMM phase: thread tile rows 4*sub..+3, cols 4q..4q+3
    const float4* W4 = (const float4*)Wl;
    float4 c0 = make_float4(0.f,0.f,0.f,0.f), c1 = c0, c2 = c0, c3 = c0;
#pragma unroll 8
    for (int k = 0; k < 64; ++k) {
        float4 w = W4[k * 16 + q];
        float a0 = T[(sub * 4 + 0) * 68 + k];
        float a1 = T[(sub * 4 + 1) * 68 + k];
        float a2 = T[(sub * 4 + 2) * 68 + k];
        float a3 = T[(sub * 4 + 3) * 68 + k];
        f4fma(a0, w, c0);
        f4fma(a1, w, c1);
        f4fma(a2, w, c2);
        f4fma(a3, w, c3);
    }
    float4 s1 = make_float4(0.f,0.f,0.f,0.f), s2 = s1;
    int nrow = node0 + sub * 4;
    float4* agg4 = (float4*)agg;
    if (nrow + 0 < NN) { agg4[(nrow + 0) * 16 + q] = c0;
        s1.x += c0.x; s1.y += c0.y; s1.z += c0.z; s1.w += c0.w;
        s2.x += c0.x*c0.x; s2.y += c0.y*c0.y; s2.z += c0.z*c0.z; s2.w += c0.w*c0.w; }
    if (nrow + 1 < NN) { agg4[(nrow + 1) * 16 + q] = c1;
        s1.x += c1.x; s1.y += c1.y; s1.z += c1.z; s1.w += c1.w;
        s2.x += c1.x*c1.x; s2.y += c1.y*c1.y; s2.z += c1.z*c1.z; s2.w += c1.w*c1.w; }
    if (nrow + 2 < NN) { agg4[(nrow + 2) * 16 + q] = c2;
        s1.x += c2.x; s1.y += c2.y; s1.z += c2.z; s1.w += c2.w;
        s2.x += c2.x*c2.x; s2.y += c2.y*c2.y; s2.z += c2.z*c2.z; s2.w += c2.w*c2.w; }
    if (nrow + 3 < NN) { agg4[(nrow + 3) * 16 + q] = c3;
        s1.x += c3.x; s1.y += c3.y; s1.z += c3.z; s1.w += c3.w;
        s2.x += c3.x*c3.x; s2.y += c3.y*c3.y; s2.z += c3.z*c3.z; s2.w += c3.w*c3.w; }
    ls0[sub][q * 4 + 0] = s1.x; ls0[sub][q * 4 + 1] = s1.y;
    ls0[sub][q * 4 + 2] = s1.z; ls0[sub][q * 4 + 3] = s1.w;
    ls1[sub][q * 4 + 0] = s2.x; ls1[sub][q * 4 + 1] = s2.y;
    ls1[sub][q * 4 + 2] = s2.z; ls1[sub][q * 4 + 3] = s2.w;
    __syncthreads();
    if (tid < 64) {
        float a = 0.f;
#pragma unroll
        for (int r = 0; r < 16; ++r) a += ls0[r][tid];
        atomicAdd(&sums[tid], a);
    } else if (tid < 128) {
        int c = tid - 64;
        float a = 0.f;
#pragma unroll
        for (int r = 0; r < 16; ++r) a += ls1[r][c];
        atomicAdd(&sums[64 + c], a);
    }
}

// ---------- x += relu(BN(agg))  (float4) ----------

__global__ __launch_bounds__(256) void k_bnupdate(const float* __restrict__ agg,
                                                  const float* __restrict__ sums,
                                                  const float* __restrict__ gamma,
                                                  const float* __restrict__ beta,
                                                  float* __restrict__ x) {
    int i = blockIdx.x * blockDim.x + threadIdx.x;
    if (i >= NN * 16) return;
    int f4 = i & 15;
    const float invn = 1.0f / (float)NN;
    float4 sm = ((const float4*)sums)[f4];
    float4 sq = ((const float4*)(sums + 64))[f4];
    float4 g = ((const float4*)gamma)[f4];
    float4 be = ((const float4*)beta)[f4];
    float4 a = ((const float4*)agg)[i];
    float4 xv = ((const float4*)x)[i];
    float mu, var, rstd, xn;
    mu = sm.x * invn; var = sq.x * invn - mu * mu; rstd = rsqrtf(var + BN_EPS);
    xn = (a.x - mu) * rstd * g.x + be.x; xv.x += fmaxf(xn, 0.f);
    mu = sm.y * invn; var = sq.y * invn - mu * mu; rstd = rsqrtf(var + BN_EPS);
    xn = (a.y - mu) * rstd * g.y + be.y; xv.y += fmaxf(xn, 0.f);
    mu = sm.z * invn; var = sq.z * invn - mu * mu; rstd = rsqrtf(var + BN_EPS);
    xn = (a.z - mu) * rstd * g.z + be.z; xv.z += fmaxf(xn, 0.f);
    mu = sm.w * invn; var = sq.w * invn - mu * mu; rstd = rsqrtf(var + BN_EPS);
    xn = (a.w - mu) * rstd * g.w + be.w; xv.w += fmaxf(xn, 0.f);
    ((float4*)x)[i] = xv;
}

// ---------- decoder (4 edges/wave, float4) ----------

__global__ __launch_bounds__(256) void k_decode(const int* __restrict__ pred,
                                                const float* __restrict__ z,
                                                float* __restrict__ out) {
    int gw = (blockIdx.x * blockDim.x + threadIdx.x) >> 6;
    int lane = threadIdx.x & 63;
    int sub = lane >> 4, q = lane & 15;
    int p = gw * 4 + sub;
    if (p >= NP) return;
    const float4* z4 = (const float4*)z;
    int a = pred[2 * p], b = pred[2 * p + 1];
    float4 va = z4[a * 16 + q];
    float4 vb = z4[b * 16 + q];
    float v = va.x * vb.x + va.y * vb.y + va.z * vb.z + va.w * vb.w;
    v += __shfl_xor(v, 1);
    v += __shfl_xor(v, 2);
    v += __shfl_xor(v, 4);
    v += __shfl_xor(v, 8);
    if (q == 0) out[p] = v;
}

extern "C" void kernel_launch(void* const* d_in, const int* in_sizes, int n_in,
                              void* d_out, int out_size, void* d_ws, size_t ws_size,
                              hipStream_t stream) {
    const int* edge_index = (const int*)d_in[0];   // [2][NE]
    const int* pred       = (const int*)d_in[1];   // [NP][2]
    const float* id_emb   = (const float*)d_in[2];
    const float* n2v      = (const float*)d_in[3];
    const float* proj_w   = (const float*)d_in[4];
    const float* proj_b   = (const float*)d_in[5];
    const float* conv_w   = (const float*)d_in[6]; // [2][64][64]
    // d_in[7] conv_b cancels inside BatchNorm -> skipped
    const float* gamma    = (const float*)d_in[8];
    const float* beta     = (const float*)d_in[9];
    float* out = (float*)d_out;

    char* ws = (char*)d_ws;
    size_t off = 0;
    float* dis  = (float*)(ws + off); off += alignup(NN * 4);
    int* cnt    = (int*)(ws + off);   off += alignup(NN * 4);
    int* offs   = (int*)(ws + off);   off += alignup((NN + 1) * 4);
    int* rank   = (int*)(ws + off);   off += alignup((size_t)NE * 4);
    int* bsum   = (int*)(ws + off);   off += alignup(NB1 * 4);
    int* boff   = (int*)(ws + off);   off += alignup(NB1 * 4);
    int2* csr   = (int2*)(ws + off);  off += alignup((size_t)NE * 8);
    float* x    = (float*)(ws + off); off += alignup((size_t)NN * 64 * 4);
    float* agg  = (float*)(ws + off); off += alignup((size_t)NN * 64 * 4);
    float* sums = (float*)(ws + off); // 256 floats

    const int* row = edge_index;
    const int* col = edge_index + NE;

    // CSR build (once, reused for both layers)
    hipMemsetAsync(cnt, 0, NN * 4, stream);
    k_count<<<(NE + 255) / 256, 256, 0, stream>>>(col, cnt, rank);
    k_dis<<<(NN + 255) / 256, 256, 0, stream>>>(cnt, dis, sums);
    k_scan1<<<NB1, 256, 0, stream>>>(cnt, offs, bsum);
    k_scan2<<<1, 256, 0, stream>>>(bsum, boff);
    k_scan3<<<NB1, 256, 0, stream>>>(offs, boff);
    k_fill<<<(NE + 255) / 256, 256, 0, stream>>>(row, col, rank, offs, dis, csr);

    k_proj<<<(NN + 31) / 32, 256, 0, stream>>>(id_emb, n2v, proj_w, proj_b, x);

    for (int l = 0; l < 2; ++l) {
        k_gg<<<(NN + 63) / 64, 256, 0, stream>>>(offs, csr, dis, x, conv_w + l * 64 * 64, agg, sums + l * 128);
        k_bnupdate<<<(NN * 16 + 255) / 256, 256, 0, stream>>>(agg, sums + l * 128, gamma + l * 64, beta + l * 64, x);
    }

    k_decode<<<(NP / 4 * 64 + 255) / 256, 256, 0, stream>>>(pred, x, out);
}

// Round 5
// 232.203 us; speedup vs baseline: 2.5252x; 1.2878x over previous
//
#include <hip/hip_runtime.h>

#define NN 50000
#define HID 64
#define NE 800000
#define NP 100000
#define BN_EPS 1e-5f
#define NB1 196   // ceil(NN/256)

static inline size_t alignup(size_t x) { return (x + 255) & ~(size_t)255; }

__device__ __forceinline__ void f4fma(float a, const float4& w, float4& c) {
    c.x += a * w.x; c.y += a * w.y; c.z += a * w.z; c.w += a * w.w;
}
__device__ __forceinline__ void f4acc(float w, const float4& a, float4& c) {
    c.x += w * a.x; c.y += w * a.y; c.z += w * a.z; c.w += w * a.w;
}

// ---------- degree count + per-edge rank ----------

__global__ __launch_bounds__(256) void k_count(const int* __restrict__ col,
                                               int* __restrict__ cnt, int* __restrict__ rank) {
    int e = blockIdx.x * blockDim.x + threadIdx.x;
    if (e < NE) rank[e] = atomicAdd(&cnt[col[e]], 1);
}

__global__ __launch_bounds__(256) void k_dis(const int* __restrict__ cnt, float* __restrict__ dis,
                                             float* __restrict__ sums) {
    int i = blockIdx.x * blockDim.x + threadIdx.x;
    if (i < NN) dis[i] = rsqrtf((float)(cnt[i] + 1));   // +1 self-loop
    if (i < 256) sums[i] = 0.f;                          // 2 layers x {sum,sumsq}
}

// ---------- exclusive scan of cnt -> offs ----------

__global__ __launch_bounds__(256) void k_scan1(const int* __restrict__ cnt,
                                               int* __restrict__ offs, int* __restrict__ bsum) {
    __shared__ int s[256];
    int t = threadIdx.x;
    int i = blockIdx.x * 256 + t;
    int v = (i < NN) ? cnt[i] : 0;
    s[t] = v;
    __syncthreads();
    for (int off = 1; off < 256; off <<= 1) {
        int add = (t >= off) ? s[t - off] : 0;
        __syncthreads();
        s[t] += add;
        __syncthreads();
    }
    if (i < NN) offs[i] = s[t] - v;
    if (t == 255) bsum[blockIdx.x] = s[255];
}

__global__ __launch_bounds__(256) void k_scan2(int* __restrict__ bsum, int* __restrict__ boff) {
    __shared__ int s[256];
    int t = threadIdx.x;
    int v = (t < NB1) ? bsum[t] : 0;
    s[t] = v;
    __syncthreads();
    for (int off = 1; off < 256; off <<= 1) {
        int add = (t >= off) ? s[t - off] : 0;
        __syncthreads();
        s[t] += add;
        __syncthreads();
    }
    if (t < NB1) boff[t] = s[t] - v;
}

__global__ __launch_bounds__(256) void k_scan3(int* __restrict__ offs, const int* __restrict__ boff) {
    int i = blockIdx.x * blockDim.x + threadIdx.x;
    if (i < NN) offs[i] += boff[i >> 8];
    if (i == 0) offs[NN] = NE;
}

// ---------- CSR fill: one 8B {src, w} store per edge, no atomics ----------

__global__ __launch_bounds__(256) void k_fill(const int* __restrict__ row, const int* __restrict__ col,
                                              const int* __restrict__ rank, const int* __restrict__ offs,
                                              const float* __restrict__ dis,
                                              int2* __restrict__ csr) {
    int e = blockIdx.x * blockDim.x + threadIdx.x;
    if (e >= NE) return;
    int s = row[e], d = col[e];
    int2 v;
    v.x = s;
    v.y = __float_as_int(dis[s] * dis[d]);
    csr[offs[d] + rank[e]] = v;
}

// ---------- input projection: register-tiled, 32 nodes x 64 cols per block ----------

__global__ __launch_bounds__(256) void k_proj(const float* __restrict__ id_emb,
                                              const float* __restrict__ n2v,
                                              const float* __restrict__ W,
                                              const float* __restrict__ b,
                                              float* __restrict__ x) {
    __shared__ float A[32 * 132];
    __shared__ float Wl[128 * 64];
    int tid = threadIdx.x;
    int node0 = blockIdx.x * 32;
    for (int i = tid; i < 128 * 64; i += 256) Wl[i] = W[i];
    for (int i = tid; i < 32 * 128; i += 256) {
        int ln = i >> 7, k = i & 127;
        int n = node0 + ln;
        float v = 0.f;
        if (n < NN) v = (k < 64) ? id_emb[n * 64 + k] : n2v[n * 64 + (k - 64)];
        A[ln * 132 + k] = v;
    }
    __syncthreads();
    int tr = tid >> 4, tc = tid & 15;
    const float4* W4 = (const float4*)Wl;
    float4 bb = ((const float4*)b)[tc];
    float4 c0 = bb, c1 = bb;
#pragma unroll 8
    for (int k = 0; k < 128; ++k) {
        float a0 = A[(tr * 2) * 132 + k];
        float a1 = A[(tr * 2 + 1) * 132 + k];
        float4 w = W4[k * 16 + tc];
        f4fma(a0, w, c0);
        f4fma(a1, w, c1);
    }
    int n0 = node0 + tr * 2;
    if (n0 < NN)     ((float4*)x)[n0 * 16 + tc] = c0;
    if (n0 + 1 < NN) ((float4*)x)[(n0 + 1) * 16 + tc] = c1;
}

// ---------- standalone CSR gather: zero LDS, high occupancy ----------
// t[n][:] = x[n]/deg + sum_j w_j x[src_j]   (4 nodes/wave, float4/lane, unroll 4)

__global__ __launch_bounds__(256) void k_gather(const int* __restrict__ offs,
                                                const int2* __restrict__ csr,
                                                const float* __restrict__ dis,
                                                const float* __restrict__ x,
                                                float* __restrict__ t) {
    int gw = (blockIdx.x * blockDim.x + threadIdx.x) >> 6;
    int lane = threadIdx.x & 63;
    int sub = lane >> 4, q = lane & 15;
    int node = gw * 4 + sub;
    if (node >= NN) return;
    const float4* x4 = (const float4*)x;
    float di = dis[node];
    float dd = di * di;
    float4 v = x4[node * 16 + q];
    float4 acc = make_float4(dd * v.x, dd * v.y, dd * v.z, dd * v.w);
    int j = offs[node], j1 = offs[node + 1];
    for (; j + 3 < j1; j += 4) {
        int2 e0 = csr[j], e1 = csr[j + 1], e2 = csr[j + 2], e3 = csr[j + 3];
        float4 a0 = x4[e0.x * 16 + q];
        float4 a1 = x4[e1.x * 16 + q];
        float4 a2 = x4[e2.x * 16 + q];
        float4 a3 = x4[e3.x * 16 + q];
        f4acc(__int_as_float(e0.y), a0, acc);
        f4acc(__int_as_float(e1.y), a1, acc);
        f4acc(__int_as_float(e2.y), a2, acc);
        f4acc(__int_as_float(e3.y), a3, acc);
    }
    for (; j < j1; ++j) {
        int2 e0 = csr[j];
        float4 a0 = x4[e0.x * 16 + q];
        f4acc(__int_as_float(e0.y), a0, acc);
    }
    ((float4*)t)[node * 16 + q] = acc;
}

// ---------- agg = t @ W with fused BN column stats (grid-stride, W resident, 4x4 reg tile) ----------

__global__ __launch_bounds__(256) void k_gemm_stats(const float* __restrict__ t,
                                                    const float* __restrict__ W,
                                                    float* __restrict__ agg,
                                                    float* __restrict__ sums) {
    __shared__ float T[64 * 68];
    __shared__ float Wl[64 * 64];
    __shared__ float ls0[16][64];
    __shared__ float ls1[16][64];
    int tid = threadIdx.x;
    for (int i = tid; i < 64 * 64; i += 256) Wl[i] = W[i];
    int sub = tid >> 4, q = tid & 15;
    const float4* t4 = (const float4*)t;
    const float4* W4 = (const float4*)Wl;
    float4* agg4 = (float4*)agg;
    float4 s1 = make_float4(0.f, 0.f, 0.f, 0.f), s2 = s1;
    const int ngroups = (NN + 63) / 64;
    for (int g = blockIdx.x; g < ngroups; g += gridDim.x) {
        __syncthreads();   // protects T (and covers initial Wl load)
        // stage 64x64 t-tile coalesced
        for (int i = tid; i < 1024; i += 256) {
            int r = i >> 4, c4 = i & 15;
            int n = g * 64 + r;
            float4 v = (n < NN) ? t4[n * 16 + c4] : make_float4(0.f, 0.f, 0.f, 0.f);
            *((float4*)(T + r * 68 + c4 * 4)) = v;
        }
        __syncthreads();
        float4 c0 = make_float4(0.f,0.f,0.f,0.f), c1 = c0, c2 = c0, c3 = c0;
#pragma unroll 8
        for (int k = 0; k < 64; ++k) {
            float4 w = W4[k * 16 + q];
            float a0 = T[(sub * 4 + 0) * 68 + k];
            float a1 = T[(sub * 4 + 1) * 68 + k];
            float a2 = T[(sub * 4 + 2) * 68 + k];
            float a3 = T[(sub * 4 + 3) * 68 + k];
            f4fma(a0, w, c0);
            f4fma(a1, w, c1);
            f4fma(a2, w, c2);
            f4fma(a3, w, c3);
        }
        int nrow = g * 64 + sub * 4;
        if (nrow + 0 < NN) { agg4[(nrow + 0) * 16 + q] = c0;
            s1.x += c0.x; s1.y += c0.y; s1.z += c0.z; s1.w += c0.w;
            s2.x += c0.x*c0.x; s2.y += c0.y*c0.y; s2.z += c0.z*c0.z; s2.w += c0.w*c0.w; }
        if (nrow + 1 < NN) { agg4[(nrow + 1) * 16 + q] = c1;
            s1.x += c1.x; s1.y += c1.y; s1.z += c1.z; s1.w += c1.w;
            s2.x += c1.x*c1.x; s2.y += c1.y*c1.y; s2.z += c1.z*c1.z; s2.w += c1.w*c1.w; }
        if (nrow + 2 < NN) { agg4[(nrow + 2) * 16 + q] = c2;
            s1.x += c2.x; s1.y += c2.y; s1.z += c2.z; s1.w += c2.w;
            s2.x += c2.x*c2.x; s2.y += c2.y*c2.y; s2.z += c2.z*c2.z; s2.w += c2.w*c2.w; }
        if (nrow + 3 < NN) { agg4[(nrow + 3) * 16 + q] = c3;
            s1.x += c3.x; s1.y += c3.y; s1.z += c3.z; s1.w += c3.w;
            s2.x += c3.x*c3.x; s2.y += c3.y*c3.y; s2.z += c3.z*c3.z; s2.w += c3.w*c3.w; }
    }
    ls0[sub][q * 4 + 0] = s1.x; ls0[sub][q * 4 + 1] = s1.y;
    ls0[sub][q * 4 + 2] = s1.z; ls0[sub][q * 4 + 3] = s1.w;
    ls1[sub][q * 4 + 0] = s2.x; ls1[sub][q * 4 + 1] = s2.y;
    ls1[sub][q * 4 + 2] = s2.z; ls1[sub][q * 4 + 3] = s2.w;
    __syncthreads();
    if (tid < 64) {
        float a = 0.f;
#pragma unroll
        for (int r = 0; r < 16; ++r) a += ls0[r][tid];
        atomicAdd(&sums[tid], a);
    } else if (tid < 128) {
        int c = tid - 64;
        float a = 0.f;
#pragma unroll
        for (int r = 0; r < 16; ++r) a += ls1[r][c];
        atomicAdd(&sums[64 + c], a);
    }
}

// ---------- x += relu(BN(agg))  (float4) ----------

__global__ __launch_bounds__(256) void k_bnupdate(const float* __restrict__ agg,
                                                  const float* __restrict__ sums,
                                                  const float* __restrict__ gamma,
                                                  const float* __restrict__ beta,
                                                  float* __restrict__ x) {
    int i = blockIdx.x * blockDim.x + threadIdx.x;
    if (i >= NN * 16) return;
    int f4 = i & 15;
    const float invn = 1.0f / (float)NN;
    float4 sm = ((const float4*)sums)[f4];
    float4 sq = ((const float4*)(sums + 64))[f4];
    float4 g = ((const float4*)gamma)[f4];
    float4 be = ((const float4*)beta)[f4];
    float4 a = ((const float4*)agg)[i];
    float4 xv = ((const float4*)x)[i];
    float mu, var, rstd, xn;
    mu = sm.x * invn; var = sq.x * invn - mu * mu; rstd = rsqrtf(var + BN_EPS);
    xn = (a.x - mu) * rstd * g.x + be.x; xv.x += fmaxf(xn, 0.f);
    mu = sm.y * invn; var = sq.y * invn - mu * mu; rstd = rsqrtf(var + BN_EPS);
    xn = (a.y - mu) * rstd * g.y + be.y; xv.y += fmaxf(xn, 0.f);
    mu = sm.z * invn; var = sq.z * invn - mu * mu; rstd = rsqrtf(var + BN_EPS);
    xn = (a.z - mu) * rstd * g.z + be.z; xv.z += fmaxf(xn, 0.f);
    mu = sm.w * invn; var = sq.w * invn - mu * mu; rstd = rsqrtf(var + BN_EPS);
    xn = (a.w - mu) * rstd * g.w + be.w; xv.w += fmaxf(xn, 0.f);
    ((float4*)x)[i] = xv;
}

// ---------- decoder (4 edges/wave, float4) ----------

__global__ __launch_bounds__(256) void k_decode(const int* __restrict__ pred,
                                                const float* __restrict__ z,
                                                float* __restrict__ out) {
    int gw = (blockIdx.x * blockDim.x + threadIdx.x) >> 6;
    int lane = threadIdx.x & 63;
    int sub = lane >> 4, q = lane & 15;
    int p = gw * 4 + sub;
    if (p >= NP) return;
    const float4* z4 = (const float4*)z;
    int a = pred[2 * p], b = pred[2 * p + 1];
    float4 va = z4[a * 16 + q];
    float4 vb = z4[b * 16 + q];
    float v = va.x * vb.x + va.y * vb.y + va.z * vb.z + va.w * vb.w;
    v += __shfl_xor(v, 1);
    v += __shfl_xor(v, 2);
    v += __shfl_xor(v, 4);
    v += __shfl_xor(v, 8);
    if (q == 0) out[p] = v;
}

extern "C" void kernel_launch(void* const* d_in, const int* in_sizes, int n_in,
                              void* d_out, int out_size, void* d_ws, size_t ws_size,
                              hipStream_t stream) {
    const int* edge_index = (const int*)d_in[0];   // [2][NE]
    const int* pred       = (const int*)d_in[1];   // [NP][2]
    const float* id_emb   = (const float*)d_in[2];
    const float* n2v      = (const float*)d_in[3];
    const float* proj_w   = (const float*)d_in[4];
    const float* proj_b   = (const float*)d_in[5];
    const float* conv_w   = (const float*)d_in[6]; // [2][64][64]
    // d_in[7] conv_b cancels inside BatchNorm -> skipped
    const float* gamma    = (const float*)d_in[8];
    const float* beta     = (const float*)d_in[9];
    float* out = (float*)d_out;

    char* ws = (char*)d_ws;
    size_t off = 0;
    float* dis  = (float*)(ws + off); off += alignup(NN * 4);
    int* cnt    = (int*)(ws + off);   off += alignup(NN * 4);
    int* offs   = (int*)(ws + off);   off += alignup((NN + 1) * 4);
    int* rank   = (int*)(ws + off);   off += alignup((size_t)NE * 4);
    int* bsum   = (int*)(ws + off);   off += alignup(NB1 * 4);
    int* boff   = (int*)(ws + off);   off += alignup(NB1 * 4);
    int2* csr   = (int2*)(ws + off);  off += alignup((size_t)NE * 8);
    float* x    = (float*)(ws + off); off += alignup((size_t)NN * 64 * 4);
    float* t    = (float*)(ws + off); off += alignup((size_t)NN * 64 * 4);
    float* agg  = (float*)(ws + off); off += alignup((size_t)NN * 64 * 4);
    float* sums = (float*)(ws + off); // 256 floats

    const int* row = edge_index;
    const int* col = edge_index + NE;

    // CSR build (once, reused for both layers)
    hipMemsetAsync(cnt, 0, NN * 4, stream);
    k_count<<<(NE + 255) / 256, 256, 0, stream>>>(col, cnt, rank);
    k_dis<<<(NN + 255) / 256, 256, 0, stream>>>(cnt, dis, sums);
    k_scan1<<<NB1, 256, 0, stream>>>(cnt, offs, bsum);
    k_scan2<<<1, 256, 0, stream>>>(bsum, boff);
    k_scan3<<<NB1, 256, 0, stream>>>(offs, boff);
    k_fill<<<(NE + 255) / 256, 256, 0, stream>>>(row, col, rank, offs, dis, csr);

    k_proj<<<(NN + 31) / 32, 256, 0, stream>>>(id_emb, n2v, proj_w, proj_b, x);

    for (int l = 0; l < 2; ++l) {
        k_gather<<<((NN + 3) / 4 * 64 + 255) / 256, 256, 0, stream>>>(offs, csr, dis, x, t);
        k_gemm_stats<<<512, 256, 0, stream>>>(t, conv_w + l * 64 * 64, agg, sums + l * 128);
        k_bnupdate<<<(NN * 16 + 255) / 256, 256, 0, stream>>>(agg, sums + l * 128, gamma + l * 64, beta + l * 64, x);
    }

    k_decode<<<(NP / 4 * 64 + 255) / 256, 256, 0, stream>>>(pred, x, out);
}

// Round 6
// 221.467 us; speedup vs baseline: 2.6476x; 1.0485x over previous
//
#include <hip/hip_runtime.h>

#define NN 50000
#define HID 64
#define NE 800000
#define NP 100000
#define BN_EPS 1e-5f
#define NB1 196   // ceil(NN/256)

static inline size_t alignup(size_t x) { return (x + 255) & ~(size_t)255; }

__device__ __forceinline__ void f4fma(float a, const float4& w, float4& c) {
    c.x += a * w.x; c.y += a * w.y; c.z += a * w.z; c.w += a * w.w;
}
__device__ __forceinline__ void f4acc(float w, const float4& a, float4& c) {
    c.x += w * a.x; c.y += w * a.y; c.z += w * a.z; c.w += w * a.w;
}
__device__ __forceinline__ unsigned bfpack(float a, float b) {
    unsigned ua = __float_as_uint(a), ub = __float_as_uint(b);
    ua = (ua + 0x7fffu + ((ua >> 16) & 1u)) >> 16;
    ub = (ub + 0x7fffu + ((ub >> 16) & 1u)) >> 16;
    return ua | (ub << 16);
}
__device__ __forceinline__ float4 bf2f4(uint2 u) {
    float4 r;
    r.x = __uint_as_float(u.x << 16);
    r.y = __uint_as_float(u.x & 0xffff0000u);
    r.z = __uint_as_float(u.y << 16);
    r.w = __uint_as_float(u.y & 0xffff0000u);
    return r;
}

// ---------- zero cnt + BN sums (replaces slow rocclr fill) ----------

__global__ __launch_bounds__(256) void k_zero(int* __restrict__ cnt, float* __restrict__ sums) {
    int i = blockIdx.x * blockDim.x + threadIdx.x;
    if (i < NN) cnt[i] = 0;
    if (i < 256) sums[i] = 0.f;
}

// ---------- degree count + per-edge rank ----------

__global__ __launch_bounds__(256) void k_count(const int* __restrict__ col,
                                               int* __restrict__ cnt, int* __restrict__ rank) {
    int e = blockIdx.x * blockDim.x + threadIdx.x;
    if (e < NE) rank[e] = atomicAdd(&cnt[col[e]], 1);
}

__global__ __launch_bounds__(256) void k_dis(const int* __restrict__ cnt, float* __restrict__ dis) {
    int i = blockIdx.x * blockDim.x + threadIdx.x;
    if (i < NN) dis[i] = rsqrtf((float)(cnt[i] + 1));   // +1 self-loop
}

// ---------- exclusive scan of cnt -> offs ----------

__global__ __launch_bounds__(256) void k_scan1(const int* __restrict__ cnt,
                                               int* __restrict__ offs, int* __restrict__ bsum) {
    __shared__ int s[256];
    int t = threadIdx.x;
    int i = blockIdx.x * 256 + t;
    int v = (i < NN) ? cnt[i] : 0;
    s[t] = v;
    __syncthreads();
    for (int off = 1; off < 256; off <<= 1) {
        int add = (t >= off) ? s[t - off] : 0;
        __syncthreads();
        s[t] += add;
        __syncthreads();
    }
    if (i < NN) offs[i] = s[t] - v;
    if (t == 255) bsum[blockIdx.x] = s[255];
}

__global__ __launch_bounds__(256) void k_scan2(int* __restrict__ bsum, int* __restrict__ boff) {
    __shared__ int s[256];
    int t = threadIdx.x;
    int v = (t < NB1) ? bsum[t] : 0;
    s[t] = v;
    __syncthreads();
    for (int off = 1; off < 256; off <<= 1) {
        int add = (t >= off) ? s[t - off] : 0;
        __syncthreads();
        s[t] += add;
        __syncthreads();
    }
    if (t < NB1) boff[t] = s[t] - v;
}

__global__ __launch_bounds__(256) void k_scan3(int* __restrict__ offs, const int* __restrict__ boff) {
    int i = blockIdx.x * blockDim.x + threadIdx.x;
    if (i < NN) offs[i] += boff[i >> 8];
    if (i == 0) offs[NN] = NE;
}

// ---------- CSR fill: one 8B {src, w} store per edge, no atomics ----------

__global__ __launch_bounds__(256) void k_fill(const int* __restrict__ row, const int* __restrict__ col,
                                              const int* __restrict__ rank, const int* __restrict__ offs,
                                              const float* __restrict__ dis,
                                              int2* __restrict__ csr) {
    int e = blockIdx.x * blockDim.x + threadIdx.x;
    if (e >= NE) return;
    int s = row[e], d = col[e];
    int2 v;
    v.x = s;
    v.y = __float_as_int(dis[s] * dis[d]);
    csr[offs[d] + rank[e]] = v;
}

// ---------- input projection: 64-node tile, all-float4 LDS reads ----------
// x = concat(id,n2v) @ W + b ; also writes bf16 mirror xh

__global__ __launch_bounds__(256) void k_proj(const float* __restrict__ id_emb,
                                              const float* __restrict__ n2v,
                                              const float* __restrict__ W,
                                              const float* __restrict__ b,
                                              float* __restrict__ x,
                                              unsigned short* __restrict__ xh) {
    __shared__ float A[64 * 132];        // 64 nodes x 128 k (pad 132)
    __shared__ float Wl[128 * 64];
    int tid = threadIdx.x;
    int node0 = blockIdx.x * 64;
    for (int i = tid; i < 128 * 64; i += 256) Wl[i] = W[i];
    for (int i = tid; i < 64 * 128; i += 256) {
        int r = i >> 7, k = i & 127;
        int n = node0 + r;
        float v = 0.f;
        if (n < NN) v = (k < 64) ? id_emb[n * 64 + k] : n2v[n * 64 + (k - 64)];
        A[r * 132 + k] = v;
    }
    __syncthreads();
    int sub = tid >> 4, q = tid & 15;    // rows sub*4..+3, cols 4q..4q+3
    const float4* W4 = (const float4*)Wl;
    float4 bb = ((const float4*)b)[q];
    float4 c0 = bb, c1 = bb, c2 = bb, c3 = bb;
#pragma unroll 4
    for (int k4 = 0; k4 < 32; ++k4) {
        int k = k4 * 4;
        float4 w0 = W4[(k + 0) * 16 + q];
        float4 w1 = W4[(k + 1) * 16 + q];
        float4 w2 = W4[(k + 2) * 16 + q];
        float4 w3 = W4[(k + 3) * 16 + q];
        float4 a;
        a = *(const float4*)&A[(sub * 4 + 0) * 132 + k];
        f4fma(a.x, w0, c0); f4fma(a.y, w1, c0); f4fma(a.z, w2, c0); f4fma(a.w, w3, c0);
        a = *(const float4*)&A[(sub * 4 + 1) * 132 + k];
        f4fma(a.x, w0, c1); f4fma(a.y, w1, c1); f4fma(a.z, w2, c1); f4fma(a.w, w3, c1);
        a = *(const float4*)&A[(sub * 4 + 2) * 132 + k];
        f4fma(a.x, w0, c2); f4fma(a.y, w1, c2); f4fma(a.z, w2, c2); f4fma(a.w, w3, c2);
        a = *(const float4*)&A[(sub * 4 + 3) * 132 + k];
        f4fma(a.x, w0, c3); f4fma(a.y, w1, c3); f4fma(a.z, w2, c3); f4fma(a.w, w3, c3);
    }
    float4* x4 = (float4*)x;
    uint2* xh2 = (uint2*)xh;
    int n0 = node0 + sub * 4;
    if (n0 + 0 < NN) { x4[(n0+0)*16+q] = c0; xh2[(n0+0)*16+q] = make_uint2(bfpack(c0.x,c0.y), bfpack(c0.z,c0.w)); }
    if (n0 + 1 < NN) { x4[(n0+1)*16+q] = c1; xh2[(n0+1)*16+q] = make_uint2(bfpack(c1.x,c1.y), bfpack(c1.z,c1.w)); }
    if (n0 + 2 < NN) { x4[(n0+2)*16+q] = c2; xh2[(n0+2)*16+q] = make_uint2(bfpack(c2.x,c2.y), bfpack(c2.z,c2.w)); }
    if (n0 + 3 < NN) { x4[(n0+3)*16+q] = c3; xh2[(n0+3)*16+q] = make_uint2(bfpack(c3.x,c3.y), bfpack(c3.z,c3.w)); }
}

// ---------- standalone CSR gather (bf16 neighbor rows): zero LDS, high occupancy ----------
// t[n][:] = x[n]/deg + sum_j w_j xh[src_j]   (4 nodes/wave, 8B/lane, unroll 4)

__global__ __launch_bounds__(256) void k_gather(const int* __restrict__ offs,
                                                const int2* __restrict__ csr,
                                                const float* __restrict__ dis,
                                                const float* __restrict__ x,
                                                const unsigned short* __restrict__ xh,
                                                float* __restrict__ t) {
    int gw = (blockIdx.x * blockDim.x + threadIdx.x) >> 6;
    int lane = threadIdx.x & 63;
    int sub = lane >> 4, q = lane & 15;
    int node = gw * 4 + sub;
    if (node >= NN) return;
    const float4* x4 = (const float4*)x;
    const uint2* xh2 = (const uint2*)xh;
    float di = dis[node];
    float dd = di * di;
    float4 v = x4[node * 16 + q];
    float4 acc = make_float4(dd * v.x, dd * v.y, dd * v.z, dd * v.w);
    int j = offs[node], j1 = offs[node + 1];
    for (; j + 3 < j1; j += 4) {
        int2 e0 = csr[j], e1 = csr[j + 1], e2 = csr[j + 2], e3 = csr[j + 3];
        uint2 u0 = xh2[e0.x * 16 + q];
        uint2 u1 = xh2[e1.x * 16 + q];
        uint2 u2 = xh2[e2.x * 16 + q];
        uint2 u3 = xh2[e3.x * 16 + q];
        f4acc(__int_as_float(e0.y), bf2f4(u0), acc);
        f4acc(__int_as_float(e1.y), bf2f4(u1), acc);
        f4acc(__int_as_float(e2.y), bf2f4(u2), acc);
        f4acc(__int_as_float(e3.y), bf2f4(u3), acc);
    }
    for (; j < j1; ++j) {
        int2 e0 = csr[j];
        uint2 u0 = xh2[e0.x * 16 + q];
        f4acc(__int_as_float(e0.y), bf2f4(u0), acc);
    }
    ((float4*)t)[node * 16 + q] = acc;
}

// ---------- agg = t @ W with fused BN column stats (grid-stride, W resident, 4x4 reg tile) ----------

__global__ __launch_bounds__(256) void k_gemm_stats(const float* __restrict__ t,
                                                    const float* __restrict__ W,
                                                    float* __restrict__ agg,
                                                    float* __restrict__ sums) {
    __shared__ float T[64 * 68];
    __shared__ float Wl[64 * 64];
    __shared__ float ls0[16][64];
    __shared__ float ls1[16][64];
    int tid = threadIdx.x;
    for (int i = tid; i < 64 * 64; i += 256) Wl[i] = W[i];
    int sub = tid >> 4, q = tid & 15;
    const float4* t4 = (const float4*)t;
    const float4* W4 = (const float4*)Wl;
    float4* agg4 = (float4*)agg;
    float4 s1 = make_float4(0.f, 0.f, 0.f, 0.f), s2 = s1;
    const int ngroups = (NN + 63) / 64;
    for (int g = blockIdx.x; g < ngroups; g += gridDim.x) {
        __syncthreads();
        for (int i = tid; i < 1024; i += 256) {
            int r = i >> 4, c4 = i & 15;
            int n = g * 64 + r;
            float4 v = (n < NN) ? t4[n * 16 + c4] : make_float4(0.f, 0.f, 0.f, 0.f);
            *((float4*)(T + r * 68 + c4 * 4)) = v;
        }
        __syncthreads();
        float4 c0 = make_float4(0.f,0.f,0.f,0.f), c1 = c0, c2 = c0, c3 = c0;
#pragma unroll 8
        for (int k = 0; k < 64; ++k) {
            float4 w = W4[k * 16 + q];
            float a0 = T[(sub * 4 + 0) * 68 + k];
            float a1 = T[(sub * 4 + 1) * 68 + k];
            float a2 = T[(sub * 4 + 2) * 68 + k];
            float a3 = T[(sub * 4 + 3) * 68 + k];
            f4fma(a0, w, c0);
            f4fma(a1, w, c1);
            f4fma(a2, w, c2);
            f4fma(a3, w, c3);
        }
        int nrow = g * 64 + sub * 4;
        if (nrow + 0 < NN) { agg4[(nrow + 0) * 16 + q] = c0;
            s1.x += c0.x; s1.y += c0.y; s1.z += c0.z; s1.w += c0.w;
            s2.x += c0.x*c0.x; s2.y += c0.y*c0.y; s2.z += c0.z*c0.z; s2.w += c0.w*c0.w; }
        if (nrow + 1 < NN) { agg4[(nrow + 1) * 16 + q] = c1;
            s1.x += c1.x; s1.y += c1.y; s1.z += c1.z; s1.w += c1.w;
            s2.x += c1.x*c1.x; s2.y += c1.y*c1.y; s2.z += c1.z*c1.z; s2.w += c1.w*c1.w; }
        if (nrow + 2 < NN) { agg4[(nrow + 2) * 16 + q] = c2;
            s1.x += c2.x; s1.y += c2.y; s1.z += c2.z; s1.w += c2.w;
            s2.x += c2.x*c2.x; s2.y += c2.y*c2.y; s2.z += c2.z*c2.z; s2.w += c2.w*c2.w; }
        if (nrow + 3 < NN) { agg4[(nrow + 3) * 16 + q] = c3;
            s1.x += c3.x; s1.y += c3.y; s1.z += c3.z; s1.w += c3.w;
            s2.x += c3.x*c3.x; s2.y += c3.y*c3.y; s2.z += c3.z*c3.z; s2.w += c3.w*c3.w; }
    }
    ls0[sub][q * 4 + 0] = s1.x; ls0[sub][q * 4 + 1] = s1.y;
    ls0[sub][q * 4 + 2] = s1.z; ls0[sub][q * 4 + 3] = s1.w;
    ls1[sub][q * 4 + 0] = s2.x; ls1[sub][q * 4 + 1] = s2.y;
    ls1[sub][q * 4 + 2] = s2.z; ls1[sub][q * 4 + 3] = s2.w;
    __syncthreads();
    if (tid < 64) {
        float a = 0.f;
#pragma unroll
        for (int r = 0; r < 16; ++r) a += ls0[r][tid];
        atomicAdd(&sums[tid], a);
    } else if (tid < 128) {
        int c = tid - 64;
        float a = 0.f;
#pragma unroll
        for (int r = 0; r < 16; ++r) a += ls1[r][c];
        atomicAdd(&sums[64 + c], a);
    }
}

// ---------- x += relu(BN(agg)); refresh bf16 mirror ----------

__global__ __launch_bounds__(256) void k_bnupdate(const float* __restrict__ agg,
                                                  const float* __restrict__ sums,
                                                  const float* __restrict__ gamma,
                                                  const float* __restrict__ beta,
                                                  float* __restrict__ x,
                                                  unsigned short* __restrict__ xh) {
    int i = blockIdx.x * blockDim.x + threadIdx.x;
    if (i >= NN * 16) return;
    int f4 = i & 15;
    const float invn = 1.0f / (float)NN;
    float4 sm = ((const float4*)sums)[f4];
    float4 sq = ((const float4*)(sums + 64))[f4];
    float4 g = ((const float4*)gamma)[f4];
    float4 be = ((const float4*)beta)[f4];
    float4 a = ((const float4*)agg)[i];
    float4 xv = ((const float4*)x)[i];
    float mu, var, rstd, xn;
    mu = sm.x * invn; var = sq.x * invn - mu * mu; rstd = rsqrtf(var + BN_EPS);
    xn = (a.x - mu) * rstd * g.x + be.x; xv.x += fmaxf(xn, 0.f);
    mu = sm.y * invn; var = sq.y * invn - mu * mu; rstd = rsqrtf(var + BN_EPS);
    xn = (a.y - mu) * rstd * g.y + be.y; xv.y += fmaxf(xn, 0.f);
    mu = sm.z * invn; var = sq.z * invn - mu * mu; rstd = rsqrtf(var + BN_EPS);
    xn = (a.z - mu) * rstd * g.z + be.z; xv.z += fmaxf(xn, 0.f);
    mu = sm.w * invn; var = sq.w * invn - mu * mu; rstd = rsqrtf(var + BN_EPS);
    xn = (a.w - mu) * rstd * g.w + be.w; xv.w += fmaxf(xn, 0.f);
    ((float4*)x)[i] = xv;
    ((uint2*)xh)[i] = make_uint2(bfpack(xv.x, xv.y), bfpack(xv.z, xv.w));
}

// ---------- decoder (bf16 rows, 4 edges/wave) ----------

__global__ __launch_bounds__(256) void k_decode(const int* __restrict__ pred,
                                                const unsigned short* __restrict__ zh,
                                                float* __restrict__ out) {
    int gw = (blockIdx.x * blockDim.x + threadIdx.x) >> 6;
    int lane = threadIdx.x & 63;
    int sub = lane >> 4, q = lane & 15;
    int p = gw * 4 + sub;
    if (p >= NP) return;
    const uint2* z2 = (const uint2*)zh;
    int a = pred[2 * p], b = pred[2 * p + 1];
    float4 va = bf2f4(z2[a * 16 + q]);
    float4 vb = bf2f4(z2[b * 16 + q]);
    float v = va.x * vb.x + va.y * vb.y + va.z * vb.z + va.w * vb.w;
    v += __shfl_xor(v, 1);
    v += __shfl_xor(v, 2);
    v += __shfl_xor(v, 4);
    v += __shfl_xor(v, 8);
    if (q == 0) out[p] = v;
}

extern "C" void kernel_launch(void* const* d_in, const int* in_sizes, int n_in,
                              void* d_out, int out_size, void* d_ws, size_t ws_size,
                              hipStream_t stream) {
    const int* edge_index = (const int*)d_in[0];   // [2][NE]
    const int* pred       = (const int*)d_in[1];   // [NP][2]
    const float* id_emb   = (const float*)d_in[2];
    const float* n2v      = (const float*)d_in[3];
    const float* proj_w   = (const float*)d_in[4];
    const float* proj_b   = (const float*)d_in[5];
    const float* conv_w   = (const float*)d_in[6]; // [2][64][64]
    // d_in[7] conv_b cancels inside BatchNorm -> skipped
    const float* gamma    = (const float*)d_in[8];
    const float* beta     = (const float*)d_in[9];
    float* out = (float*)d_out;

    char* ws = (char*)d_ws;
    size_t off = 0;
    float* dis  = (float*)(ws + off); off += alignup(NN * 4);
    int* cnt    = (int*)(ws + off);   off += alignup(NN * 4);
    int* offs   = (int*)(ws + off);   off += alignup((NN + 1) * 4);
    int* rank   = (int*)(ws + off);   off += alignup((size_t)NE * 4);
    int* bsum   = (int*)(ws + off);   off += alignup(NB1 * 4);
    int* boff   = (int*)(ws + off);   off += alignup(NB1 * 4);
    int2* csr   = (int2*)(ws + off);  off += alignup((size_t)NE * 8);
    float* x    = (float*)(ws + off); off += alignup((size_t)NN * 64 * 4);
    float* t    = (float*)(ws + off); off += alignup((size_t)NN * 64 * 4);
    float* agg  = (float*)(ws + off); off += alignup((size_t)NN * 64 * 4);
    unsigned short* xh = (unsigned short*)(ws + off); off += alignup((size_t)NN * 64 * 2);
    float* sums = (float*)(ws + off); // 256 floats

    const int* row = edge_index;
    const int* col = edge_index + NE;

    // CSR build (once, reused for both layers)
    k_zero<<<NB1, 256, 0, stream>>>(cnt, sums);
    k_count<<<(NE + 255) / 256, 256, 0, stream>>>(col, cnt, rank);
    k_dis<<<(NN + 255) / 256, 256, 0, stream>>>(cnt, dis);
    k_scan1<<<NB1, 256, 0, stream>>>(cnt, offs, bsum);
    k_scan2<<<1, 256, 0, stream>>>(bsum, boff);
    k_scan3<<<NB1, 256, 0, stream>>>(offs, boff);
    k_fill<<<(NE + 255) / 256, 256, 0, stream>>>(row, col, rank, offs, dis, csr);

    k_proj<<<(NN + 63) / 64, 256, 0, stream>>>(id_emb, n2v, proj_w, proj_b, x, xh);

    for (int l = 0; l < 2; ++l) {
        k_gather<<<((NN + 3) / 4 * 64 + 255) / 256, 256, 0, stream>>>(offs, csr, dis, x, xh, t);
        k_gemm_stats<<<512, 256, 0, stream>>>(t, conv_w + l * 64 * 64, agg, sums + l * 128);
        k_bnupdate<<<(NN * 16 + 255) / 256, 256, 0, stream>>>(agg, sums + l * 128, gamma + l * 64, beta + l * 64, x, xh);
    }

    k_decode<<<(NP / 4 * 64 + 255) / 256, 256, 0, stream>>>(pred, xh, out);
}

// Round 7
// 213.047 us; speedup vs baseline: 2.7523x; 1.0395x over previous
//
#include <hip/hip_runtime.h>

#define NN 50000
#define HID 64
#define NE 800000
#define NP 100000
#define BN_EPS 1e-5f
#define NB1 196   // ceil(NN/256)

static inline size_t alignup(size_t x) { return (x + 255) & ~(size_t)255; }

__device__ __forceinline__ void f4fma(float a, const float4& w, float4& c) {
    c.x += a * w.x; c.y += a * w.y; c.z += a * w.z; c.w += a * w.w;
}
__device__ __forceinline__ void f4acc(float w, const float4& a, float4& c) {
    c.x += w * a.x; c.y += w * a.y; c.z += w * a.z; c.w += w * a.w;
}
__device__ __forceinline__ unsigned bfpack(float a, float b) {
    unsigned ua = __float_as_uint(a), ub = __float_as_uint(b);
    ua = (ua + 0x7fffu + ((ua >> 16) & 1u)) >> 16;
    ub = (ub + 0x7fffu + ((ub >> 16) & 1u)) >> 16;
    return ua | (ub << 16);
}
__device__ __forceinline__ float4 bf2f4(uint2 u) {
    float4 r;
    r.x = __uint_as_float(u.x << 16);
    r.y = __uint_as_float(u.x & 0xffff0000u);
    r.z = __uint_as_float(u.y << 16);
    r.w = __uint_as_float(u.y & 0xffff0000u);
    return r;
}

// ---------- zero cnt + BN sums ----------

__global__ __launch_bounds__(256) void k_zero(int* __restrict__ cnt, float* __restrict__ sums) {
    int i = blockIdx.x * blockDim.x + threadIdx.x;
    if (i < NN) cnt[i] = 0;
    if (i < 256) sums[i] = 0.f;
}

// ---------- degree count + per-edge rank ----------

__global__ __launch_bounds__(256) void k_count(const int* __restrict__ col,
                                               int* __restrict__ cnt, int* __restrict__ rank) {
    int e = blockIdx.x * blockDim.x + threadIdx.x;
    if (e < NE) rank[e] = atomicAdd(&cnt[col[e]], 1);
}

// ---------- exclusive scan of cnt -> offs (also emits dis) ----------

__global__ __launch_bounds__(256) void k_scan1(const int* __restrict__ cnt,
                                               int* __restrict__ offs, int* __restrict__ bsum,
                                               float* __restrict__ dis) {
    __shared__ int s[256];
    int t = threadIdx.x;
    int i = blockIdx.x * 256 + t;
    int v = (i < NN) ? cnt[i] : 0;
    if (i < NN) dis[i] = rsqrtf((float)(v + 1));   // +1 self-loop
    s[t] = v;
    __syncthreads();
    for (int off = 1; off < 256; off <<= 1) {
        int add = (t >= off) ? s[t - off] : 0;
        __syncthreads();
        s[t] += add;
        __syncthreads();
    }
    if (i < NN) offs[i] = s[t] - v;
    if (t == 255) bsum[blockIdx.x] = s[255];
}

__global__ __launch_bounds__(256) void k_scan2(int* __restrict__ bsum, int* __restrict__ boff) {
    __shared__ int s[256];
    int t = threadIdx.x;
    int v = (t < NB1) ? bsum[t] : 0;
    s[t] = v;
    __syncthreads();
    for (int off = 1; off < 256; off <<= 1) {
        int add = (t >= off) ? s[t - off] : 0;
        __syncthreads();
        s[t] += add;
        __syncthreads();
    }
    if (t < NB1) boff[t] = s[t] - v;
}

__global__ __launch_bounds__(256) void k_scan3(int* __restrict__ offs, const int* __restrict__ boff) {
    int i = blockIdx.x * blockDim.x + threadIdx.x;
    if (i < NN) offs[i] += boff[i >> 8];
    if (i == 0) offs[NN] = NE;
}

// ---------- CSR fill ----------

__global__ __launch_bounds__(256) void k_fill(const int* __restrict__ row, const int* __restrict__ col,
                                              const int* __restrict__ rank, const int* __restrict__ offs,
                                              const float* __restrict__ dis,
                                              int2* __restrict__ csr) {
    int e = blockIdx.x * blockDim.x + threadIdx.x;
    if (e >= NE) return;
    int s = row[e], d = col[e];
    int2 v;
    v.x = s;
    v.y = __float_as_int(dis[s] * dis[d]);
    csr[offs[d] + rank[e]] = v;
}

// ---------- input projection: W in LDS only, A direct from global (broadcast), no barriers ----------

__global__ __launch_bounds__(256) void k_proj(const float* __restrict__ id_emb,
                                              const float* __restrict__ n2v,
                                              const float* __restrict__ W,
                                              const float* __restrict__ b,
                                              float* __restrict__ x,
                                              unsigned short* __restrict__ xh) {
    __shared__ float Wl[128 * 64];
    int tid = threadIdx.x;
    for (int i = tid; i < 128 * 64; i += 256) Wl[i] = W[i];
    __syncthreads();
    int sub = tid >> 4, q = tid & 15;
    const float4* W4 = (const float4*)Wl;
    const float4* id4 = (const float4*)id_emb;
    const float4* nv4 = (const float4*)n2v;
    float4* x4 = (float4*)x;
    uint2* xh2 = (uint2*)xh;
    float4 bb = ((const float4*)b)[q];
    const int ngroups = (NN + 63) / 64;
    for (int g = blockIdx.x; g < ngroups; g += gridDim.x) {
        int n0 = g * 64 + sub * 4;
        int r0 = min(n0 + 0, NN - 1), r1 = min(n0 + 1, NN - 1);
        int r2 = min(n0 + 2, NN - 1), r3 = min(n0 + 3, NN - 1);
        float4 c0 = bb, c1 = bb, c2 = bb, c3 = bb;
#pragma unroll 4
        for (int k4 = 0; k4 < 16; ++k4) {        // K 0..63: id_emb
            float4 a0 = id4[r0 * 16 + k4];
            float4 a1 = id4[r1 * 16 + k4];
            float4 a2 = id4[r2 * 16 + k4];
            float4 a3 = id4[r3 * 16 + k4];
            float4 w0 = W4[(k4 * 4 + 0) * 16 + q];
            float4 w1 = W4[(k4 * 4 + 1) * 16 + q];
            float4 w2 = W4[(k4 * 4 + 2) * 16 + q];
            float4 w3 = W4[(k4 * 4 + 3) * 16 + q];
            f4fma(a0.x, w0, c0); f4fma(a0.y, w1, c0); f4fma(a0.z, w2, c0); f4fma(a0.w, w3, c0);
            f4fma(a1.x, w0, c1); f4fma(a1.y, w1, c1); f4fma(a1.z, w2, c1); f4fma(a1.w, w3, c1);
            f4fma(a2.x, w0, c2); f4fma(a2.y, w1, c2); f4fma(a2.z, w2, c2); f4fma(a2.w, w3, c2);
            f4fma(a3.x, w0, c3); f4fma(a3.y, w1, c3); f4fma(a3.z, w2, c3); f4fma(a3.w, w3, c3);
        }
#pragma unroll 4
        for (int k4 = 0; k4 < 16; ++k4) {        // K 64..127: n2v
            float4 a0 = nv4[r0 * 16 + k4];
            float4 a1 = nv4[r1 * 16 + k4];
            float4 a2 = nv4[r2 * 16 + k4];
            float4 a3 = nv4[r3 * 16 + k4];
            float4 w0 = W4[(k4 * 4 + 64) * 16 + q];
            float4 w1 = W4[(k4 * 4 + 65) * 16 + q];
            float4 w2 = W4[(k4 * 4 + 66) * 16 + q];
            float4 w3 = W4[(k4 * 4 + 67) * 16 + q];
            f4fma(a0.x, w0, c0); f4fma(a0.y, w1, c0); f4fma(a0.z, w2, c0); f4fma(a0.w, w3, c0);
            f4fma(a1.x, w0, c1); f4fma(a1.y, w1, c1); f4fma(a1.z, w2, c1); f4fma(a1.w, w3, c1);
            f4fma(a2.x, w0, c2); f4fma(a2.y, w1, c2); f4fma(a2.z, w2, c2); f4fma(a2.w, w3, c2);
            f4fma(a3.x, w0, c3); f4fma(a3.y, w1, c3); f4fma(a3.z, w2, c3); f4fma(a3.w, w3, c3);
        }
        if (n0 + 0 < NN) { x4[(n0+0)*16+q] = c0; xh2[(n0+0)*16+q] = make_uint2(bfpack(c0.x,c0.y), bfpack(c0.z,c0.w)); }
        if (n0 + 1 < NN) { x4[(n0+1)*16+q] = c1; xh2[(n0+1)*16+q] = make_uint2(bfpack(c1.x,c1.y), bfpack(c1.z,c1.w)); }
        if (n0 + 2 < NN) { x4[(n0+2)*16+q] = c2; xh2[(n0+2)*16+q] = make_uint2(bfpack(c2.x,c2.y), bfpack(c2.z,c2.w)); }
        if (n0 + 3 < NN) { x4[(n0+3)*16+q] = c3; xh2[(n0+3)*16+q] = make_uint2(bfpack(c3.x,c3.y), bfpack(c3.z,c3.w)); }
    }
}

// ---------- CSR gather (bf16 rows) -> bf16 th ----------

__global__ __launch_bounds__(256) void k_gather(const int* __restrict__ offs,
                                                const int2* __restrict__ csr,
                                                const float* __restrict__ dis,
                                                const float* __restrict__ x,
                                                const unsigned short* __restrict__ xh,
                                                unsigned short* __restrict__ th) {
    int gw = (blockIdx.x * blockDim.x + threadIdx.x) >> 6;
    int lane = threadIdx.x & 63;
    int sub = lane >> 4, q = lane & 15;
    int node = gw * 4 + sub;
    if (node >= NN) return;
    const float4* x4 = (const float4*)x;
    const uint2* xh2 = (const uint2*)xh;
    float di = dis[node];
    float dd = di * di;
    float4 v = x4[node * 16 + q];
    float4 acc = make_float4(dd * v.x, dd * v.y, dd * v.z, dd * v.w);
    int j = offs[node], j1 = offs[node + 1];
    for (; j + 7 < j1; j += 8) {
        int2 e0 = csr[j],     e1 = csr[j + 1], e2 = csr[j + 2], e3 = csr[j + 3];
        int2 e4 = csr[j + 4], e5 = csr[j + 5], e6 = csr[j + 6], e7 = csr[j + 7];
        uint2 u0 = xh2[e0.x * 16 + q];
        uint2 u1 = xh2[e1.x * 16 + q];
        uint2 u2 = xh2[e2.x * 16 + q];
        uint2 u3 = xh2[e3.x * 16 + q];
        uint2 u4 = xh2[e4.x * 16 + q];
        uint2 u5 = xh2[e5.x * 16 + q];
        uint2 u6 = xh2[e6.x * 16 + q];
        uint2 u7 = xh2[e7.x * 16 + q];
        f4acc(__int_as_float(e0.y), bf2f4(u0), acc);
        f4acc(__int_as_float(e1.y), bf2f4(u1), acc);
        f4acc(__int_as_float(e2.y), bf2f4(u2), acc);
        f4acc(__int_as_float(e3.y), bf2f4(u3), acc);
        f4acc(__int_as_float(e4.y), bf2f4(u4), acc);
        f4acc(__int_as_float(e5.y), bf2f4(u5), acc);
        f4acc(__int_as_float(e6.y), bf2f4(u6), acc);
        f4acc(__int_as_float(e7.y), bf2f4(u7), acc);
    }
    for (; j < j1; ++j) {
        int2 e0 = csr[j];
        uint2 u0 = xh2[e0.x * 16 + q];
        f4acc(__int_as_float(e0.y), bf2f4(u0), acc);
    }
    ((uint2*)th)[node * 16 + q] = make_uint2(bfpack(acc.x, acc.y), bfpack(acc.z, acc.w));
}

// ---------- agg = th @ W + BN stats: W in LDS, th direct from global, no per-group barriers ----------

__global__ __launch_bounds__(256) void k_gemm_stats(const unsigned short* __restrict__ th,
                                                    const float* __restrict__ W,
                                                    float* __restrict__ agg,
                                                    float* __restrict__ sums) {
    __shared__ float Wl[64 * 64];
    __shared__ float ls0[16][64];
    __shared__ float ls1[16][64];
    int tid = threadIdx.x;
    for (int i = tid; i < 64 * 64; i += 256) Wl[i] = W[i];
    __syncthreads();
    int sub = tid >> 4, q = tid & 15;
    const uint2* t2 = (const uint2*)th;
    const float4* W4 = (const float4*)Wl;
    float4* agg4 = (float4*)agg;
    float4 s1 = make_float4(0.f, 0.f, 0.f, 0.f), s2 = s1;
    const int ngroups = (NN + 63) / 64;
    for (int g = blockIdx.x; g < ngroups; g += gridDim.x) {
        int n0 = g * 64 + sub * 4;
        int r0 = min(n0 + 0, NN - 1), r1 = min(n0 + 1, NN - 1);
        int r2 = min(n0 + 2, NN - 1), r3 = min(n0 + 3, NN - 1);
        float4 c0 = make_float4(0.f,0.f,0.f,0.f), c1 = c0, c2 = c0, c3 = c0;
#pragma unroll 4
        for (int k4 = 0; k4 < 16; ++k4) {
            float4 a0 = bf2f4(t2[r0 * 16 + k4]);
            float4 a1 = bf2f4(t2[r1 * 16 + k4]);
            float4 a2 = bf2f4(t2[r2 * 16 + k4]);
            float4 a3 = bf2f4(t2[r3 * 16 + k4]);
            float4 w0 = W4[(k4 * 4 + 0) * 16 + q];
            float4 w1 = W4[(k4 * 4 + 1) * 16 + q];
            float4 w2 = W4[(k4 * 4 + 2) * 16 + q];
            float4 w3 = W4[(k4 * 4 + 3) * 16 + q];
            f4fma(a0.x, w0, c0); f4fma(a0.y, w1, c0); f4fma(a0.z, w2, c0); f4fma(a0.w, w3, c0);
            f4fma(a1.x, w0, c1); f4fma(a1.y, w1, c1); f4fma(a1.z, w2, c1); f4fma(a1.w, w3, c1);
            f4fma(a2.x, w0, c2); f4fma(a2.y, w1, c2); f4fma(a2.z, w2, c2); f4fma(a2.w, w3, c2);
            f4fma(a3.x, w0, c3); f4fma(a3.y, w1, c3); f4fma(a3.z, w2, c3); f4fma(a3.w, w3, c3);
        }
        if (n0 + 0 < NN) { agg4[(n0 + 0) * 16 + q] = c0;
            s1.x += c0.x; s1.y += c0.y; s1.z += c0.z; s1.w += c0.w;
            s2.x += c0.x*c0.x; s2.y += c0.y*c0.y; s2.z += c0.z*c0.z; s2.w += c0.w*c0.w; }
        if (n0 + 1 < NN) { agg4[(n0 + 1) * 16 + q] = c1;
            s1.x += c1.x; s1.y += c1.y; s1.z += c1.z; s1.w += c1.w;
            s2.x += c1.x*c1.x; s2.y += c1.y*c1.y; s2.z += c1.z*c1.z; s2.w += c1.w*c1.w; }
        if (n0 + 2 < NN) { agg4[(n0 + 2) * 16 + q] = c2;
            s1.x += c2.x; s1.y += c2.y; s1.z += c2.z; s1.w += c2.w;
            s2.x += c2.x*c2.x; s2.y += c2.y*c2.y; s2.z += c2.z*c2.z; s2.w += c2.w*c2.w; }
        if (n0 + 3 < NN) { agg4[(n0 + 3) * 16 + q] = c3;
            s1.x += c3.x; s1.y += c3.y; s1.z += c3.z; s1.w += c3.w;
            s2.x += c3.x*c3.x; s2.y += c3.y*c3.y; s2.z += c3.z*c3.z; s2.w += c3.w*c3.w; }
    }
    ls0[sub][q * 4 + 0] = s1.x; ls0[sub][q * 4 + 1] = s1.y;
    ls0[sub][q * 4 + 2] = s1.z; ls0[sub][q * 4 + 3] = s1.w;
    ls1[sub][q * 4 + 0] = s2.x; ls1[sub][q * 4 + 1] = s2.y;
    ls1[sub][q * 4 + 2] = s2.z; ls1[sub][q * 4 + 3] = s2.w;
    __syncthreads();
    if (tid < 64) {
        float a = 0.f;
#pragma unroll
        for (int r = 0; r < 16; ++r) a += ls0[r][tid];
        atomicAdd(&sums[tid], a);
    } else if (tid < 128) {
        int c = tid - 64;
        float a = 0.f;
#pragma unroll
        for (int r = 0; r < 16; ++r) a += ls1[r][c];
        atomicAdd(&sums[64 + c], a);
    }
}

// ---------- x += relu(BN(agg)); refresh bf16 mirror ----------

__global__ __launch_bounds__(256) void k_bnupdate(const float* __restrict__ agg,
                                                  const float* __restrict__ sums,
                                                  const float* __restrict__ gamma,
                                                  const float* __restrict__ beta,
                                                  float* __restrict__ x,
                                                  unsigned short* __restrict__ xh) {
    int i = blockIdx.x * blockDim.x + threadIdx.x;
    if (i >= NN * 16) return;
    int f4 = i & 15;
    const float invn = 1.0f / (float)NN;
    float4 sm = ((const float4*)sums)[f4];
    float4 sq = ((const float4*)(sums + 64))[f4];
    float4 g = ((const float4*)gamma)[f4];
    float4 be = ((const float4*)beta)[f4];
    float4 a = ((const float4*)agg)[i];
    float4 xv = ((const float4*)x)[i];
    float mu, var, rstd, xn;
    mu = sm.x * invn; var = sq.x * invn - mu * mu; rstd = rsqrtf(var + BN_EPS);
    xn = (a.x - mu) * rstd * g.x + be.x; xv.x += fmaxf(xn, 0.f);
    mu = sm.y * invn; var = sq.y * invn - mu * mu; rstd = rsqrtf(var + BN_EPS);
    xn = (a.y - mu) * rstd * g.y + be.y; xv.y += fmaxf(xn, 0.f);
    mu = sm.z * invn; var = sq.z * invn - mu * mu; rstd = rsqrtf(var + BN_EPS);
    xn = (a.z - mu) * rstd * g.z + be.z; xv.z += fmaxf(xn, 0.f);
    mu = sm.w * invn; var = sq.w * invn - mu * mu; rstd = rsqrtf(var + BN_EPS);
    xn = (a.w - mu) * rstd * g.w + be.w; xv.w += fmaxf(xn, 0.f);
    ((float4*)x)[i] = xv;
    ((uint2*)xh)[i] = make_uint2(bfpack(xv.x, xv.y), bfpack(xv.z, xv.w));
}

// ---------- decoder (bf16 rows, 4 edges/wave) ----------

__global__ __launch_bounds__(256) void k_decode(const int* __restrict__ pred,
                                                const unsigned short* __restrict__ zh,
                                                float* __restrict__ out) {
    int gw = (blockIdx.x * blockDim.x + threadIdx.x) >> 6;
    int lane = threadIdx.x & 63;
    int sub = lane >> 4, q = lane & 15;
    int p = gw * 4 + sub;
    if (p >= NP) return;
    const uint2* z2 = (const uint2*)zh;
    int a = pred[2 * p], b = pred[2 * p + 1];
    float4 va = bf2f4(z2[a * 16 + q]);
    float4 vb = bf2f4(z2[b * 16 + q]);
    float v = va.x * vb.x + va.y * vb.y + va.z * vb.z + va.w * vb.w;
    v += __shfl_xor(v, 1);
    v += __shfl_xor(v, 2);
    v += __shfl_xor(v, 4);
    v += __shfl_xor(v, 8);
    if (q == 0) out[p] = v;
}

extern "C" void kernel_launch(void* const* d_in, const int* in_sizes, int n_in,
                              void* d_out, int out_size, void* d_ws, size_t ws_size,
                              hipStream_t stream) {
    const int* edge_index = (const int*)d_in[0];   // [2][NE]
    const int* pred       = (const int*)d_in[1];   // [NP][2]
    const float* id_emb   = (const float*)d_in[2];
    const float* n2v      = (const float*)d_in[3];
    const float* proj_w   = (const float*)d_in[4];
    const float* proj_b   = (const float*)d_in[5];
    const float* conv_w   = (const float*)d_in[6]; // [2][64][64]
    // d_in[7] conv_b cancels inside BatchNorm -> skipped
    const float* gamma    = (const float*)d_in[8];
    const float* beta     = (const float*)d_in[9];
    float* out = (float*)d_out;

    char* ws = (char*)d_ws;
    size_t off = 0;
    float* dis  = (float*)(ws + off); off += alignup(NN * 4);
    int* cnt    = (int*)(ws + off);   off += alignup(NN * 4);
    int* offs   = (int*)(ws + off);   off += alignup((NN + 1) * 4);
    int* rank   = (int*)(ws + off);   off += alignup((size_t)NE * 4);
    int* bsum   = (int*)(ws + off);   off += alignup(NB1 * 4);
    int* boff   = (int*)(ws + off);   off += alignup(NB1 * 4);
    int2* csr   = (int2*)(ws + off);  off += alignup((size_t)NE * 8);
    float* x    = (float*)(ws + off); off += alignup((size_t)NN * 64 * 4);
    float* agg  = (float*)(ws + off); off += alignup((size_t)NN * 64 * 4);
    unsigned short* xh = (unsigned short*)(ws + off); off += alignup((size_t)NN * 64 * 2);
    unsigned short* th = (unsigned short*)(ws + off); off += alignup((size_t)NN * 64 * 2);
    float* sums = (float*)(ws + off); // 256 floats

    const int* row = edge_index;
    const int* col = edge_index + NE;

    // CSR build (once, reused for both layers)
    k_zero<<<NB1, 256, 0, stream>>>(cnt, sums);
    k_count<<<(NE + 255) / 256, 256, 0, stream>>>(col, cnt, rank);
    k_scan1<<<NB1, 256, 0, stream>>>(cnt, offs, bsum, dis);
    k_scan2<<<1, 256, 0, stream>>>(bsum, boff);
    k_scan3<<<NB1, 256, 0, stream>>>(offs, boff);
    k_fill<<<(NE + 255) / 256, 256, 0, stream>>>(row, col, rank, offs, dis, csr);

    k_proj<<<512, 256, 0, stream>>>(id_emb, n2v, proj_w, proj_b, x, xh);

    for (int l = 0; l < 2; ++l) {
        k_gather<<<((NN + 3) / 4 * 64 + 255) / 256, 256, 0, stream>>>(offs, csr, dis, x, xh, th);
        k_gemm_stats<<<512, 256, 0, stream>>>(th, conv_w + l * 64 * 64, agg, sums + l * 128);
        k_bnupdate<<<(NN * 16 + 255) / 256, 256, 0, stream>>>(agg, sums + l * 128, gamma + l * 64, beta + l * 64, x, xh);
    }

    k_decode<<<(NP / 4 * 64 + 255) / 256, 256, 0, stream>>>(pred, xh, out);
}

// Round 8
// 207.565 us; speedup vs baseline: 2.8249x; 1.0264x over previous
//
#include <hip/hip_runtime.h>

#define NN 50000
#define HID 64
#define NE 800000
#define NP 100000
#define BN_EPS 1e-5f
#define NB1 196   // ceil(NN/256)

static inline size_t alignup(size_t x) { return (x + 255) & ~(size_t)255; }

__device__ __forceinline__ void f4fma(float a, const float4& w, float4& c) {
    c.x += a * w.x; c.y += a * w.y; c.z += a * w.z; c.w += a * w.w;
}
__device__ __forceinline__ void f4add(const float4& a, float4& c) {
    c.x += a.x; c.y += a.y; c.z += a.z; c.w += a.w;
}
__device__ __forceinline__ unsigned bfpack(float a, float b) {
    unsigned ua = __float_as_uint(a), ub = __float_as_uint(b);
    ua = (ua + 0x7fffu + ((ua >> 16) & 1u)) >> 16;
    ub = (ub + 0x7fffu + ((ub >> 16) & 1u)) >> 16;
    return ua | (ub << 16);
}
__device__ __forceinline__ float4 bf2f4(uint2 u) {
    float4 r;
    r.x = __uint_as_float(u.x << 16);
    r.y = __uint_as_float(u.x & 0xffff0000u);
    r.z = __uint_as_float(u.y << 16);
    r.w = __uint_as_float(u.y & 0xffff0000u);
    return r;
}

// ---------- zero cnt + BN sums ----------

__global__ __launch_bounds__(256) void k_zero(int* __restrict__ cnt, float* __restrict__ sums) {
    int i = blockIdx.x * blockDim.x + threadIdx.x;
    if (i < NN) cnt[i] = 0;
    if (i < 256) sums[i] = 0.f;
}

// ---------- degree count + per-edge rank ----------

__global__ __launch_bounds__(256) void k_count(const int* __restrict__ col,
                                               int* __restrict__ cnt, int* __restrict__ rank) {
    int e = blockIdx.x * blockDim.x + threadIdx.x;
    if (e < NE) rank[e] = atomicAdd(&cnt[col[e]], 1);
}

// ---------- exclusive scan of cnt -> offs (also emits dis) ----------

__global__ __launch_bounds__(256) void k_scan1(const int* __restrict__ cnt,
                                               int* __restrict__ offs, int* __restrict__ bsum,
                                               float* __restrict__ dis) {
    __shared__ int s[256];
    int t = threadIdx.x;
    int i = blockIdx.x * 256 + t;
    int v = (i < NN) ? cnt[i] : 0;
    if (i < NN) dis[i] = rsqrtf((float)(v + 1));   // +1 self-loop
    s[t] = v;
    __syncthreads();
    for (int off = 1; off < 256; off <<= 1) {
        int add = (t >= off) ? s[t - off] : 0;
        __syncthreads();
        s[t] += add;
        __syncthreads();
    }
    if (i < NN) offs[i] = s[t] - v;
    if (t == 255) bsum[blockIdx.x] = s[255];
}

__global__ __launch_bounds__(256) void k_scan2(int* __restrict__ bsum, int* __restrict__ boff) {
    __shared__ int s[256];
    int t = threadIdx.x;
    int v = (t < NB1) ? bsum[t] : 0;
    s[t] = v;
    __syncthreads();
    for (int off = 1; off < 256; off <<= 1) {
        int add = (t >= off) ? s[t - off] : 0;
        __syncthreads();
        s[t] += add;
        __syncthreads();
    }
    if (t < NB1) boff[t] = s[t] - v;
}

__global__ __launch_bounds__(256) void k_scan3(int* __restrict__ offs, const int* __restrict__ boff) {
    int i = blockIdx.x * blockDim.x + threadIdx.x;
    if (i < NN) offs[i] += boff[i >> 8];
    if (i == 0) offs[NN] = NE;
}

// ---------- CSR fill: single 4B src-index store per edge (weights factored out) ----------

__global__ __launch_bounds__(256) void k_fill(const int* __restrict__ row, const int* __restrict__ col,
                                              const int* __restrict__ rank, const int* __restrict__ offs,
                                              int* __restrict__ csr_src) {
    int e = blockIdx.x * blockDim.x + threadIdx.x;
    if (e >= NE) return;
    csr_src[offs[col[e]] + rank[e]] = row[e];
}

// ---------- input projection: W in LDS, A direct from global (broadcast), no per-group barriers ----------
// x = concat(id,n2v) @ W + b ; xh = bf16(dis * x)   (prescaled mirror)

__global__ __launch_bounds__(256) void k_proj(const float* __restrict__ id_emb,
                                              const float* __restrict__ n2v,
                                              const float* __restrict__ W,
                                              const float* __restrict__ b,
                                              const float* __restrict__ dis,
                                              float* __restrict__ x,
                                              unsigned short* __restrict__ xh) {
    __shared__ float Wl[128 * 64];
    int tid = threadIdx.x;
    for (int i = tid; i < 128 * 64; i += 256) Wl[i] = W[i];
    __syncthreads();
    int sub = tid >> 4, q = tid & 15;
    const float4* W4 = (const float4*)Wl;
    const float4* id4 = (const float4*)id_emb;
    const float4* nv4 = (const float4*)n2v;
    float4* x4 = (float4*)x;
    uint2* xh2 = (uint2*)xh;
    float4 bb = ((const float4*)b)[q];
    const int ngroups = (NN + 63) / 64;
    for (int g = blockIdx.x; g < ngroups; g += gridDim.x) {
        int n0 = g * 64 + sub * 4;
        int r0 = min(n0 + 0, NN - 1), r1 = min(n0 + 1, NN - 1);
        int r2 = min(n0 + 2, NN - 1), r3 = min(n0 + 3, NN - 1);
        float4 c0 = bb, c1 = bb, c2 = bb, c3 = bb;
#pragma unroll 4
        for (int k4 = 0; k4 < 16; ++k4) {        // K 0..63: id_emb
            float4 a0 = id4[r0 * 16 + k4];
            float4 a1 = id4[r1 * 16 + k4];
            float4 a2 = id4[r2 * 16 + k4];
            float4 a3 = id4[r3 * 16 + k4];
            float4 w0 = W4[(k4 * 4 + 0) * 16 + q];
            float4 w1 = W4[(k4 * 4 + 1) * 16 + q];
            float4 w2 = W4[(k4 * 4 + 2) * 16 + q];
            float4 w3 = W4[(k4 * 4 + 3) * 16 + q];
            f4fma(a0.x, w0, c0); f4fma(a0.y, w1, c0); f4fma(a0.z, w2, c0); f4fma(a0.w, w3, c0);
            f4fma(a1.x, w0, c1); f4fma(a1.y, w1, c1); f4fma(a1.z, w2, c1); f4fma(a1.w, w3, c1);
            f4fma(a2.x, w0, c2); f4fma(a2.y, w1, c2); f4fma(a2.z, w2, c2); f4fma(a2.w, w3, c2);
            f4fma(a3.x, w0, c3); f4fma(a3.y, w1, c3); f4fma(a3.z, w2, c3); f4fma(a3.w, w3, c3);
        }
#pragma unroll 4
        for (int k4 = 0; k4 < 16; ++k4) {        // K 64..127: n2v
            float4 a0 = nv4[r0 * 16 + k4];
            float4 a1 = nv4[r1 * 16 + k4];
            float4 a2 = nv4[r2 * 16 + k4];
            float4 a3 = nv4[r3 * 16 + k4];
            float4 w0 = W4[(k4 * 4 + 64) * 16 + q];
            float4 w1 = W4[(k4 * 4 + 65) * 16 + q];
            float4 w2 = W4[(k4 * 4 + 66) * 16 + q];
            float4 w3 = W4[(k4 * 4 + 67) * 16 + q];
            f4fma(a0.x, w0, c0); f4fma(a0.y, w1, c0); f4fma(a0.z, w2, c0); f4fma(a0.w, w3, c0);
            f4fma(a1.x, w0, c1); f4fma(a1.y, w1, c1); f4fma(a1.z, w2, c1); f4fma(a1.w, w3, c1);
            f4fma(a2.x, w0, c2); f4fma(a2.y, w1, c2); f4fma(a2.z, w2, c2); f4fma(a2.w, w3, c2);
            f4fma(a3.x, w0, c3); f4fma(a3.y, w1, c3); f4fma(a3.z, w2, c3); f4fma(a3.w, w3, c3);
        }
        if (n0 + 0 < NN) { float d = dis[n0+0]; x4[(n0+0)*16+q] = c0;
            xh2[(n0+0)*16+q] = make_uint2(bfpack(c0.x*d,c0.y*d), bfpack(c0.z*d,c0.w*d)); }
        if (n0 + 1 < NN) { float d = dis[n0+1]; x4[(n0+1)*16+q] = c1;
            xh2[(n0+1)*16+q] = make_uint2(bfpack(c1.x*d,c1.y*d), bfpack(c1.z*d,c1.w*d)); }
        if (n0 + 2 < NN) { float d = dis[n0+2]; x4[(n0+2)*16+q] = c2;
            xh2[(n0+2)*16+q] = make_uint2(bfpack(c2.x*d,c2.y*d), bfpack(c2.z*d,c2.w*d)); }
        if (n0 + 3 < NN) { float d = dis[n0+3]; x4[(n0+3)*16+q] = c3;
            xh2[(n0+3)*16+q] = make_uint2(bfpack(c3.x*d,c3.y*d), bfpack(c3.z*d,c3.w*d)); }
    }
}

// ---------- CSR gather, weight-free inner loop ----------
// t[d] = dis[d] * ( sum_j xh[src_j] + dis[d]*x[d] )   with xh = dis*x prescaled

__global__ __launch_bounds__(256) void k_gather(const int* __restrict__ offs,
                                                const int* __restrict__ csr_src,
                                                const float* __restrict__ dis,
                                                const float* __restrict__ x,
                                                const unsigned short* __restrict__ xh,
                                                unsigned short* __restrict__ th) {
    int gw = (blockIdx.x * blockDim.x + threadIdx.x) >> 6;
    int lane = threadIdx.x & 63;
    int sub = lane >> 4, q = lane & 15;
    int node = gw * 4 + sub;
    if (node >= NN) return;
    const float4* x4 = (const float4*)x;
    const uint2* xh2 = (const uint2*)xh;
    float4 acc = make_float4(0.f, 0.f, 0.f, 0.f);
    int j = offs[node], j1 = offs[node + 1];
    for (; j + 7 < j1; j += 8) {
        int s0 = csr_src[j],     s1 = csr_src[j + 1], s2 = csr_src[j + 2], s3 = csr_src[j + 3];
        int s4 = csr_src[j + 4], s5 = csr_src[j + 5], s6 = csr_src[j + 6], s7 = csr_src[j + 7];
        uint2 u0 = xh2[s0 * 16 + q];
        uint2 u1 = xh2[s1 * 16 + q];
        uint2 u2 = xh2[s2 * 16 + q];
        uint2 u3 = xh2[s3 * 16 + q];
        uint2 u4 = xh2[s4 * 16 + q];
        uint2 u5 = xh2[s5 * 16 + q];
        uint2 u6 = xh2[s6 * 16 + q];
        uint2 u7 = xh2[s7 * 16 + q];
        f4add(bf2f4(u0), acc); f4add(bf2f4(u1), acc);
        f4add(bf2f4(u2), acc); f4add(bf2f4(u3), acc);
        f4add(bf2f4(u4), acc); f4add(bf2f4(u5), acc);
        f4add(bf2f4(u6), acc); f4add(bf2f4(u7), acc);
    }
    for (; j < j1; ++j) {
        uint2 u0 = xh2[csr_src[j] * 16 + q];
        f4add(bf2f4(u0), acc);
    }
    float di = dis[node];
    float4 v = x4[node * 16 + q];
    acc.x = di * (acc.x + di * v.x);
    acc.y = di * (acc.y + di * v.y);
    acc.z = di * (acc.z + di * v.z);
    acc.w = di * (acc.w + di * v.w);
    ((uint2*)th)[node * 16 + q] = make_uint2(bfpack(acc.x, acc.y), bfpack(acc.z, acc.w));
}

// ---------- agg = th @ W + BN stats: W in LDS, th direct from global ----------

__global__ __launch_bounds__(256) void k_gemm_stats(const unsigned short* __restrict__ th,
                                                    const float* __restrict__ W,
                                                    float* __restrict__ agg,
                                                    float* __restrict__ sums) {
    __shared__ float Wl[64 * 64];
    __shared__ float ls0[16][64];
    __shared__ float ls1[16][64];
    int tid = threadIdx.x;
    for (int i = tid; i < 64 * 64; i += 256) Wl[i] = W[i];
    __syncthreads();
    int sub = tid >> 4, q = tid & 15;
    const uint2* t2 = (const uint2*)th;
    const float4* W4 = (const float4*)Wl;
    float4* agg4 = (float4*)agg;
    float4 s1 = make_float4(0.f, 0.f, 0.f, 0.f), s2 = s1;
    const int ngroups = (NN + 63) / 64;
    for (int g = blockIdx.x; g < ngroups; g += gridDim.x) {
        int n0 = g * 64 + sub * 4;
        int r0 = min(n0 + 0, NN - 1), r1 = min(n0 + 1, NN - 1);
        int r2 = min(n0 + 2, NN - 1), r3 = min(n0 + 3, NN - 1);
        float4 c0 = make_float4(0.f,0.f,0.f,0.f), c1 = c0, c2 = c0, c3 = c0;
#pragma unroll 4
        for (int k4 = 0; k4 < 16; ++k4) {
            float4 a0 = bf2f4(t2[r0 * 16 + k4]);
            float4 a1 = bf2f4(t2[r1 * 16 + k4]);
            float4 a2 = bf2f4(t2[r2 * 16 + k4]);
            float4 a3 = bf2f4(t2[r3 * 16 + k4]);
            float4 w0 = W4[(k4 * 4 + 0) * 16 + q];
            float4 w1 = W4[(k4 * 4 + 1) * 16 + q];
            float4 w2 = W4[(k4 * 4 + 2) * 16 + q];
            float4 w3 = W4[(k4 * 4 + 3) * 16 + q];
            f4fma(a0.x, w0, c0); f4fma(a0.y, w1, c0); f4fma(a0.z, w2, c0); f4fma(a0.w, w3, c0);
            f4fma(a1.x, w0, c1); f4fma(a1.y, w1, c1); f4fma(a1.z, w2, c1); f4fma(a1.w, w3, c1);
            f4fma(a2.x, w0, c2); f4fma(a2.y, w1, c2); f4fma(a2.z, w2, c2); f4fma(a2.w, w3, c2);
            f4fma(a3.x, w0, c3); f4fma(a3.y, w1, c3); f4fma(a3.z, w2, c3); f4fma(a3.w, w3, c3);
        }
        if (n0 + 0 < NN) { agg4[(n0 + 0) * 16 + q] = c0;
            s1.x += c0.x; s1.y += c0.y; s1.z += c0.z; s1.w += c0.w;
            s2.x += c0.x*c0.x; s2.y += c0.y*c0.y; s2.z += c0.z*c0.z; s2.w += c0.w*c0.w; }
        if (n0 + 1 < NN) { agg4[(n0 + 1) * 16 + q] = c1;
            s1.x += c1.x; s1.y += c1.y; s1.z += c1.z; s1.w += c1.w;
            s2.x += c1.x*c1.x; s2.y += c1.y*c1.y; s2.z += c1.z*c1.z; s2.w += c1.w*c1.w; }
        if (n0 + 2 < NN) { agg4[(n0 + 2) * 16 + q] = c2;
            s1.x += c2.x; s1.y += c2.y; s1.z += c2.z; s1.w += c2.w;
            s2.x += c2.x*c2.x; s2.y += c2.y*c2.y; s2.z += c2.z*c2.z; s2.w += c2.w*c2.w; }
        if (n0 + 3 < NN) { agg4[(n0 + 3) * 16 + q] = c3;
            s1.x += c3.x; s1.y += c3.y; s1.z += c3.z; s1.w += c3.w;
            s2.x += c3.x*c3.x; s2.y += c3.y*c3.y; s2.z += c3.z*c3.z; s2.w += c3.w*c3.w; }
    }
    ls0[sub][q * 4 + 0] = s1.x; ls0[sub][q * 4 + 1] = s1.y;
    ls0[sub][q * 4 + 2] = s1.z; ls0[sub][q * 4 + 3] = s1.w;
    ls1[sub][q * 4 + 0] = s2.x; ls1[sub][q * 4 + 1] = s2.y;
    ls1[sub][q * 4 + 2] = s2.z; ls1[sub][q * 4 + 3] = s2.w;
    __syncthreads();
    if (tid < 64) {
        float a = 0.f;
#pragma unroll
        for (int r = 0; r < 16; ++r) a += ls0[r][tid];
        atomicAdd(&sums[tid], a);
    } else if (tid < 128) {
        int c = tid - 64;
        float a = 0.f;
#pragma unroll
        for (int r = 0; r < 16; ++r) a += ls1[r][c];
        atomicAdd(&sums[64 + c], a);
    }
}

// ---------- x += relu(BN(agg)); refresh bf16 mirror (prescaled except final layer) ----------

__global__ __launch_bounds__(256) void k_bnupdate(const float* __restrict__ agg,
                                                  const float* __restrict__ sums,
                                                  const float* __restrict__ gamma,
                                                  const float* __restrict__ beta,
                                                  const float* __restrict__ dis,
                                                  int prescale,
                                                  float* __restrict__ x,
                                                  unsigned short* __restrict__ xh) {
    int i = blockIdx.x * blockDim.x + threadIdx.x;
    if (i >= NN * 16) return;
    int f4 = i & 15;
    const float invn = 1.0f / (float)NN;
    float4 sm = ((const float4*)sums)[f4];
    float4 sq = ((const float4*)(sums + 64))[f4];
    float4 g = ((const float4*)gamma)[f4];
    float4 be = ((const float4*)beta)[f4];
    float4 a = ((const float4*)agg)[i];
    float4 xv = ((const float4*)x)[i];
    float mu, var, rstd, xn;
    mu = sm.x * invn; var = sq.x * invn - mu * mu; rstd = rsqrtf(var + BN_EPS);
    xn = (a.x - mu) * rstd * g.x + be.x; xv.x += fmaxf(xn, 0.f);
    mu = sm.y * invn; var = sq.y * invn - mu * mu; rstd = rsqrtf(var + BN_EPS);
    xn = (a.y - mu) * rstd * g.y + be.y; xv.y += fmaxf(xn, 0.f);
    mu = sm.z * invn; var = sq.z * invn - mu * mu; rstd = rsqrtf(var + BN_EPS);
    xn = (a.z - mu) * rstd * g.z + be.z; xv.z += fmaxf(xn, 0.f);
    mu = sm.w * invn; var = sq.w * invn - mu * mu; rstd = rsqrtf(var + BN_EPS);
    xn = (a.w - mu) * rstd * g.w + be.w; xv.w += fmaxf(xn, 0.f);
    ((float4*)x)[i] = xv;
    float d = prescale ? dis[i >> 4] : 1.0f;
    ((uint2*)xh)[i] = make_uint2(bfpack(xv.x * d, xv.y * d), bfpack(xv.z * d, xv.w * d));
}

// ---------- decoder (bf16 rows, 4 edges/wave) ----------

__global__ __launch_bounds__(256) void k_decode(const int* __restrict__ pred,
                                                const unsigned short* __restrict__ zh,
                                                float* __restrict__ out) {
    int gw = (blockIdx.x * blockDim.x + threadIdx.x) >> 6;
    int lane = threadIdx.x & 63;
    int sub = lane >> 4, q = lane & 15;
    int p = gw * 4 + sub;
    if (p >= NP) return;
    const uint2* z2 = (const uint2*)zh;
    int a = pred[2 * p], b = pred[2 * p + 1];
    float4 va = bf2f4(z2[a * 16 + q]);
    float4 vb = bf2f4(z2[b * 16 + q]);
    float v = va.x * vb.x + va.y * vb.y + va.z * vb.z + va.w * vb.w;
    v += __shfl_xor(v, 1);
    v += __shfl_xor(v, 2);
    v += __shfl_xor(v, 4);
    v += __shfl_xor(v, 8);
    if (q == 0) out[p] = v;
}

extern "C" void kernel_launch(void* const* d_in, const int* in_sizes, int n_in,
                              void* d_out, int out_size, void* d_ws, size_t ws_size,
                              hipStream_t stream) {
    const int* edge_index = (const int*)d_in[0];   // [2][NE]
    const int* pred       = (const int*)d_in[1];   // [NP][2]
    const float* id_emb   = (const float*)d_in[2];
    const float* n2v      = (const float*)d_in[3];
    const float* proj_w   = (const float*)d_in[4];
    const float* proj_b   = (const float*)d_in[5];
    const float* conv_w   = (const float*)d_in[6]; // [2][64][64]
    // d_in[7] conv_b cancels inside BatchNorm -> skipped
    const float* gamma    = (const float*)d_in[8];
    const float* beta     = (const float*)d_in[9];
    float* out = (float*)d_out;

    char* ws = (char*)d_ws;
    size_t off = 0;
    float* dis   = (float*)(ws + off); off += alignup(NN * 4);
    int* cnt     = (int*)(ws + off);   off += alignup(NN * 4);
    int* offs    = (int*)(ws + off);   off += alignup((NN + 1) * 4);
    int* rank    = (int*)(ws + off);   off += alignup((size_t)NE * 4);
    int* bsum    = (int*)(ws + off);   off += alignup(NB1 * 4);
    int* boff    = (int*)(ws + off);   off += alignup(NB1 * 4);
    int* csr_src = (int*)(ws + off);   off += alignup((size_t)NE * 4);
    float* x     = (float*)(ws + off); off += alignup((size_t)NN * 64 * 4);
    float* agg   = (float*)(ws + off); off += alignup((size_t)NN * 64 * 4);
    unsigned short* xh = (unsigned short*)(ws + off); off += alignup((size_t)NN * 64 * 2);
    unsigned short* th = (unsigned short*)(ws + off); off += alignup((size_t)NN * 64 * 2);
    float* sums  = (float*)(ws + off); // 256 floats

    const int* row = edge_index;
    const int* col = edge_index + NE;

    // CSR build (once, reused for both layers)
    k_zero<<<NB1, 256, 0, stream>>>(cnt, sums);
    k_count<<<(NE + 255) / 256, 256, 0, stream>>>(col, cnt, rank);
    k_scan1<<<NB1, 256, 0, stream>>>(cnt, offs, bsum, dis);
    k_scan2<<<1, 256, 0, stream>>>(bsum, boff);
    k_scan3<<<NB1, 256, 0, stream>>>(offs, boff);
    k_fill<<<(NE + 255) / 256, 256, 0, stream>>>(row, col, rank, offs, csr_src);

    k_proj<<<512, 256, 0, stream>>>(id_emb, n2v, proj_w, proj_b, dis, x, xh);

    for (int l = 0; l < 2; ++l) {
        k_gather<<<((NN + 3) / 4 * 64 + 255) / 256, 256, 0, stream>>>(offs, csr_src, dis, x, xh, th);
        k_gemm_stats<<<512, 256, 0, stream>>>(th, conv_w + l * 64 * 64, agg, sums + l * 128);
        k_bnupdate<<<(NN * 16 + 255) / 256, 256, 0, stream>>>(agg, sums + l * 128, gamma + l * 64,
                                                              beta + l * 64, dis, (l == 0) ? 1 : 0, x, xh);
    }

    k_decode<<<(NP / 4 * 64 + 255) / 256, 256, 0, stream>>>(pred, xh, out);
}